// Round 7
// baseline (1259.173 us; speedup 1.0000x reference)
//
#include <hip/hip_runtime.h>
#include <hip/hip_bf16.h>
#include <math.h>

#define B_ 8
#define S_ 1024
#define F_ 75
#define D_ 128
#define INNER_ 256
#define NH_ 4
#define DH_ 64
#define MROWS_ (B_*S_)   // 8192

static __device__ __forceinline__ float frcp(float x){ return __builtin_amdgcn_rcpf(x); }
static __device__ __forceinline__ float fsigm(float x){ return frcp(1.0f + __expf(-x)); }
static __device__ __forceinline__ float flogsig(float x){
    return fminf(x, 0.f) - __logf(1.0f + __expf(-fabsf(x)));
}
static __device__ __forceinline__ float ftanh(float z){
    return 1.0f - 2.0f*frcp(__expf(2.0f*z) + 1.0f);
}

// ---------------- Tiled GEMM: C = A @ W^T + bias (+ res) ----------------
__global__ __launch_bounds__(256, 2) void gemm_bias_big(
        const float* __restrict__ A, const float* __restrict__ W,
        const float* __restrict__ bias, const float* __restrict__ res,
        float* __restrict__ C, int M, int N, int K) {
    __shared__ float As[64*68];
    __shared__ float Ws[64*68];
    int tid = threadIdx.x;
    int wid = tid >> 6, lane = tid & 63;
    int wy = wid >> 1, wx = wid & 1;
    int sg = lane >> 3, tg = lane & 7;
    int m0 = blockIdx.y*64, n0 = blockIdx.x*64;
    int r = tid >> 2, c0 = (tid & 3) << 4;
    bool vec = ((K & 3) == 0);
    float acc[4][4];
    #pragma unroll
    for (int i = 0; i < 4; ++i)
        #pragma unroll
        for (int j = 0; j < 4; ++j) acc[i][j] = 0.f;

    for (int k0 = 0; k0 < K; k0 += 64) {
        __syncthreads();
        const float* Ar = A + (size_t)(m0+r)*K + k0;
        const float* Wr = W + (size_t)(n0+r)*K + k0;
        if (vec) {
            #pragma unroll
            for (int i = 0; i < 4; ++i) {
                *(float4*)(&As[r*68 + c0 + 4*i]) = *(const float4*)(Ar + c0 + 4*i);
                *(float4*)(&Ws[r*68 + c0 + 4*i]) = *(const float4*)(Wr + c0 + 4*i);
            }
        } else {
            #pragma unroll
            for (int i = 0; i < 4; ++i)
                #pragma unroll
                for (int e = 0; e < 4; ++e) {
                    int c = c0 + 4*i + e;
                    bool ok = (k0 + c) < K;
                    As[r*68 + c] = ok ? Ar[c] : 0.f;
                    Ws[r*68 + c] = ok ? Wr[c] : 0.f;
                }
        }
        __syncthreads();
        const float* arow = &As[(32*wy + sg)*68];
        const float* brow = &Ws[(32*wx + tg)*68];
        #pragma unroll 2
        for (int d = 0; d < 64; d += 4) {
            float4 b0 = *(const float4*)(brow + 0*544 + d);
            float4 b1 = *(const float4*)(brow + 1*544 + d);
            float4 b2 = *(const float4*)(brow + 2*544 + d);
            float4 b3 = *(const float4*)(brow + 3*544 + d);
            #pragma unroll
            for (int i = 0; i < 4; ++i) {
                float4 a = *(const float4*)(arow + i*544 + d);
                acc[i][0] += a.x*b0.x + a.y*b0.y + a.z*b0.z + a.w*b0.w;
                acc[i][1] += a.x*b1.x + a.y*b1.y + a.z*b1.z + a.w*b1.w;
                acc[i][2] += a.x*b2.x + a.y*b2.y + a.z*b2.z + a.w*b2.w;
                acc[i][3] += a.x*b3.x + a.y*b3.y + a.z*b3.z + a.w*b3.w;
            }
        }
    }
    #pragma unroll
    for (int i = 0; i < 4; ++i) {
        int m = m0 + 32*wy + 8*i + sg;
        #pragma unroll
        for (int j = 0; j < 4; ++j) {
            int n = n0 + 32*wx + 8*j + tg;
            float v = acc[i][j] + bias[n];
            if (res) v += res[(size_t)m*N + n];
            C[(size_t)m*N + n] = v;
        }
    }
}

// ---------------- Plain LayerNorm over D=128 ----------------
__global__ void ln_kernel(const float* __restrict__ X, const float* __restrict__ w,
                          float* __restrict__ Y) {
    int row = blockIdx.x, t = threadIdx.x;  // 128 threads
    float v = X[(size_t)row*128 + t];
    __shared__ float s1[128], s2[128];
    s1[t]=v; s2[t]=v*v; __syncthreads();
    for (int off=64; off>0; off>>=1){
        if (t<off){ s1[t]+=s1[t+off]; s2[t]+=s2[t+off]; }
        __syncthreads();
    }
    float mu = s1[0]*(1.f/128.f);
    float var = s2[0]*(1.f/128.f) - mu*mu;
    Y[(size_t)row*128 + t] = (v-mu)*rsqrtf(var+1e-5f)*w[t];
}

// ---------------- Causal depthwise conv (K=4) + SiLU ----------------
__global__ void conv_silu(const float* __restrict__ X, int ldx,
                          const float* __restrict__ kw, const float* __restrict__ kb,
                          float* __restrict__ Y, int ldy, int C) {
    int idx = blockIdx.x*blockDim.x + threadIdx.x;
    int total = MROWS_*C;
    if (idx >= total) return;
    int c = idx % C; int bs = idx / C;
    int s = bs % S_; int b = bs / S_;
    float acc = kb[c];
    #pragma unroll
    for (int i = 0; i < 4; ++i) {
        int sp = s - 3 + i;
        if (sp >= 0) acc += X[((size_t)b*S_+sp)*ldx + c] * kw[c*4+i];
    }
    Y[((size_t)b*S_+s)*ldy + c] = acc * fsigm(acc);
}

// ---------------- Headwise block-diagonal proj (mLSTM q/k/v, HS=4) ----------------
__global__ void headwise4(const float* __restrict__ X, int ldx,
                          const float* __restrict__ W, const float* __restrict__ bias,
                          float* __restrict__ Y) {
    int idx = blockIdx.x*blockDim.x + threadIdx.x;
    int total = MROWS_*INNER_;
    if (idx >= total) return;
    int co = idx % INNER_; int bs = idx / INNER_;
    int h = co >> 2, o = co & 3;
    const float* Wh = W + ((size_t)h*4 + o)*4;
    const float* xr = X + (size_t)bs*ldx + h*4;
    float acc = bias[co];
    #pragma unroll
    for (int i = 0; i < 4; ++i) acc += xr[i]*Wh[i];
    Y[(size_t)bs*INNER_ + co] = acc;
}

// ---------------- sLSTM all-4-gates headwise (HS=32) ----------------
__global__ void slstm_gates(const float* __restrict__ rc, const float* __restrict__ r,
                            const float* __restrict__ Wi, const float* __restrict__ Wf,
                            const float* __restrict__ Wz, const float* __restrict__ Wo,
                            float* __restrict__ GX) {
    int idx = blockIdx.x*blockDim.x + threadIdx.x;
    int total = MROWS_*128;
    if (idx >= total) return;
    int co = idx % 128; int bs = idx / 128;
    int h = co >> 5, o = co & 31;
    size_t wb = ((size_t)h*32 + o)*32;
    const float* xc_ = rc + (size_t)bs*128 + h*32;
    const float* xr_ = r  + (size_t)bs*128 + h*32;
    float di=0.f, df=0.f, dz=0.f, doo=0.f;
    #pragma unroll
    for (int i = 0; i < 32; ++i) {
        float a = xc_[i], c = xr_[i];
        di  += a*Wi[wb+i];
        df  += a*Wf[wb+i];
        dz  += c*Wz[wb+i];
        doo += c*Wo[wb+i];
    }
    float* g = GX + (size_t)bs*512 + h*128 + o;
    g[0]  = di;
    g[32] = df;
    g[64] = dz;
    g[96] = doo;
}

// ---------------- ig/fg gate projection over concat(q,k,v) ----------------
__global__ void gateproj(const float* __restrict__ q, const float* __restrict__ k,
                         const float* __restrict__ v,
                         const float* __restrict__ Wig, const float* __restrict__ big,
                         const float* __restrict__ Wfg, const float* __restrict__ bfg,
                         float* __restrict__ igp, float* __restrict__ fgp) {
    int bs = blockIdx.x; int lane = threadIdx.x;  // 64 threads
    int b = bs / S_, s = bs % S_;
    const float* qr = q + (size_t)bs*INNER_;
    const float* kr = k + (size_t)bs*INNER_;
    const float* vr = v + (size_t)bs*INNER_;
    float dots[8];
    #pragma unroll
    for (int g=0; g<8; ++g) dots[g]=0.f;
    for (int c = lane; c < INNER_; c += 64) {
        float qv = qr[c], kv = kr[c], vv = vr[c];
        #pragma unroll
        for (int g=0; g<4; ++g) {
            dots[g]   += qv*Wig[g*768+c] + kv*Wig[g*768+256+c] + vv*Wig[g*768+512+c];
            dots[4+g] += qv*Wfg[g*768+c] + kv*Wfg[g*768+256+c] + vv*Wfg[g*768+512+c];
        }
    }
    #pragma unroll
    for (int off=32; off>0; off>>=1)
        #pragma unroll
        for (int g=0; g<8; ++g) dots[g] += __shfl_down(dots[g], off, 64);
    if (lane == 0) {
        #pragma unroll
        for (int g=0; g<4; ++g) {
            igp[((size_t)b*NH_+g)*S_ + s] = dots[g]   + big[g];
            fgp[((size_t)b*NH_+g)*S_ + s] = dots[4+g] + bfg[g];
        }
    }
}

// ---------------- mLSTM decay precompute ----------------
__global__ void mlstm_scan_pre(const float* __restrict__ igp, const float* __restrict__ fgp,
                               float* __restrict__ lc, float* __restrict__ av,
                               float* __restrict__ mx) {
    int bh = blockIdx.x; int t = threadIdx.x;  // 1024 threads
    __shared__ float buf[2][1024];
    float ls = flogsig(fgp[(size_t)bh*S_ + t]);
    int cur = 0;
    buf[0][t] = ls; __syncthreads();
    for (int off=1; off<1024; off<<=1) {
        float x2 = buf[cur][t];
        if (t >= off) x2 += buf[cur][t-off];
        buf[cur^1][t] = x2; cur ^= 1; __syncthreads();
    }
    float lcv = buf[cur][t];
    lc[(size_t)bh*S_+t] = lcv;
    float a = igp[(size_t)bh*S_+t] - lcv;
    av[(size_t)bh*S_+t] = a;
    __syncthreads();
    cur = 0; buf[0][t] = a; __syncthreads();
    for (int off=1; off<1024; off<<=1) {
        float x2 = buf[cur][t];
        if (t >= off) x2 = fmaxf(x2, buf[cur][t-off]);
        buf[cur^1][t] = x2; cur ^= 1; __syncthreads();
    }
    mx[(size_t)bh*S_+t] = buf[cur][t];
}

// ---------------- mLSTM attention: tiled flash-style ----------------
__global__ __launch_bounds__(256, 2) void mlstm_attn_tiled(
        const float* __restrict__ q, const float* __restrict__ k,
        const float* __restrict__ v, const float* __restrict__ lc,
        const float* __restrict__ av, const float* __restrict__ mx,
        float* __restrict__ hc) {
    int bid = blockIdx.x;
    int stile = 15 - (bid & 15);
    int bh = bid >> 4;
    int hh = bh & 3, b = bh >> 2;
    int s0 = stile << 6;
    int tid = threadIdx.x;
    int wid = tid >> 6, lane = tid & 63;
    int wy = wid >> 1, wx = wid & 1;
    int sg = lane >> 3, tg = lane & 7;

    __shared__ float qs[64*68];
    __shared__ float kst[64*68];
    __shared__ float vtT[64*68];
    __shared__ float avt[64], maxsL[64], normL[64], rsumL[128];

    const size_t bhS = (size_t)bh * S_;
    {
        int r = tid >> 2, c0 = (tid & 3) << 4;
        const float* qg = q + ((size_t)(b*S_) + s0 + r)*INNER_ + hh*64;
        #pragma unroll
        for (int i = 0; i < 4; ++i) {
            float4 t4 = *(const float4*)(qg + c0 + 4*i);
            float4 w4; w4.x=t4.x*0.125f; w4.y=t4.y*0.125f; w4.z=t4.z*0.125f; w4.w=t4.w*0.125f;
            *(float4*)(&qs[r*68 + c0 + 4*i]) = w4;
        }
        if (tid < 64) maxsL[tid] = lc[bhS + s0 + tid] + mx[bhS + s0 + tid];
    }
    float msv[4];
    #pragma unroll
    for (int i = 0; i < 4; ++i)
        msv[i] = mx[bhS + s0 + 32*wy + 8*i + sg];

    float O[4][4];
    float rsAcc[4];
    #pragma unroll
    for (int i = 0; i < 4; ++i) {
        rsAcc[i] = 0.f;
        #pragma unroll
        for (int j = 0; j < 4; ++j) O[i][j] = 0.f;
    }

    for (int t0 = 0; t0 <= s0; t0 += 64) {
        __syncthreads();
        {
            int r = tid >> 2, c0 = (tid & 3) << 4;
            const float* kg = k + ((size_t)(b*S_) + t0 + r)*INNER_ + hh*64;
            const float* vg = v + ((size_t)(b*S_) + t0 + r)*INNER_ + hh*64;
            #pragma unroll
            for (int i = 0; i < 4; ++i) {
                *(float4*)(&kst[r*68 + c0 + 4*i]) = *(const float4*)(kg + c0 + 4*i);
                float4 v4 = *(const float4*)(vg + c0 + 4*i);
                int dc = c0 + 4*i;
                vtT[(dc+0)*68 + r] = v4.x;
                vtT[(dc+1)*68 + r] = v4.y;
                vtT[(dc+2)*68 + r] = v4.z;
                vtT[(dc+3)*68 + r] = v4.w;
            }
            if (tid < 64) avt[tid] = av[bhS + t0 + tid];
        }
        __syncthreads();
        float dot[4][4];
        #pragma unroll
        for (int i = 0; i < 4; ++i)
            #pragma unroll
            for (int j = 0; j < 4; ++j) dot[i][j] = 0.f;
        {
            const float* qrow = &qs[(32*wy + sg)*68];
            const float* krow = &kst[(32*wx + tg)*68];
            #pragma unroll 2
            for (int d = 0; d < 64; d += 4) {
                float4 b0 = *(const float4*)(krow + 0*544 + d);
                float4 b1 = *(const float4*)(krow + 1*544 + d);
                float4 b2 = *(const float4*)(krow + 2*544 + d);
                float4 b3 = *(const float4*)(krow + 3*544 + d);
                #pragma unroll
                for (int i = 0; i < 4; ++i) {
                    float4 a = *(const float4*)(qrow + i*544 + d);
                    dot[i][0] += a.x*b0.x + a.y*b0.y + a.z*b0.z + a.w*b0.w;
                    dot[i][1] += a.x*b1.x + a.y*b1.y + a.z*b1.z + a.w*b1.w;
                    dot[i][2] += a.x*b2.x + a.y*b2.y + a.z*b2.z + a.w*b2.w;
                    dot[i][3] += a.x*b3.x + a.y*b3.y + a.z*b3.z + a.w*b3.w;
                }
            }
        }
        __syncthreads();
        #pragma unroll
        for (int i = 0; i < 4; ++i) {
            int s_loc = 32*wy + 8*i + sg;
            float rp = 0.f;
            #pragma unroll
            for (int j = 0; j < 4; ++j) {
                int t_loc = 32*wx + 8*j + tg;
                bool ok = (t0 + t_loc) <= (s0 + s_loc);
                float p = ok ? dot[i][j]*__expf(avt[t_loc] - msv[i]) : 0.f;
                kst[s_loc*68 + t_loc] = p;
                rp += p;
            }
            rp += __shfl_xor(rp, 1);
            rp += __shfl_xor(rp, 2);
            rp += __shfl_xor(rp, 4);
            rsAcc[i] += rp;
        }
        __syncthreads();
        {
            const float* prow = &kst[(32*wy + sg)*68];
            const float* vrow = &vtT[(32*wx + tg)*68];
            #pragma unroll 2
            for (int tt = 0; tt < 64; tt += 4) {
                float4 b0 = *(const float4*)(vrow + 0*544 + tt);
                float4 b1 = *(const float4*)(vrow + 1*544 + tt);
                float4 b2 = *(const float4*)(vrow + 2*544 + tt);
                float4 b3 = *(const float4*)(vrow + 3*544 + tt);
                #pragma unroll
                for (int i = 0; i < 4; ++i) {
                    float4 a = *(const float4*)(prow + i*544 + tt);
                    O[i][0] += a.x*b0.x + a.y*b0.y + a.z*b0.z + a.w*b0.w;
                    O[i][1] += a.x*b1.x + a.y*b1.y + a.z*b1.z + a.w*b1.w;
                    O[i][2] += a.x*b2.x + a.y*b2.y + a.z*b2.z + a.w*b2.w;
                    O[i][3] += a.x*b3.x + a.y*b3.y + a.z*b3.z + a.w*b3.w;
                }
            }
        }
    }
    if (tg == 0) {
        #pragma unroll
        for (int i = 0; i < 4; ++i)
            rsumL[wx*64 + 32*wy + 8*i + sg] = rsAcc[i];
    }
    __syncthreads();
    if (tid < 64) {
        float tot = rsumL[tid] + rsumL[64 + tid];
        normL[tid] = fmaxf(fabsf(tot), __expf(-maxsL[tid])) + 1e-6f;
    }
    __syncthreads();
    #pragma unroll
    for (int i = 0; i < 4; ++i) {
        int s_loc = 32*wy + 8*i + sg;
        float inv = 1.0f / normL[s_loc];
        #pragma unroll
        for (int j = 0; j < 4; ++j) {
            int d_loc = 32*wx + 8*j + tg;
            hc[((size_t)(b*S_) + s0 + s_loc)*INNER_ + hh*64 + d_loc] = O[i][j] * inv;
        }
    }
}

// ---------------- mLSTM output: multihead LN (GS=64) + skip + gate ----------------
__global__ void mlstm_out(const float* __restrict__ hc, const float* __restrict__ xc,
                          const float* __restrict__ up, const float* __restrict__ onw,
                          const float* __restrict__ skip, float* __restrict__ hs) {
    int row = blockIdx.x; int c = threadIdx.x;  // 256 threads
    float v = hc[(size_t)row*INNER_ + c];
    __shared__ float s1[256], s2[256];
    s1[c]=v; s2[c]=v*v; __syncthreads();
    int li = c & 63;
    for (int off=32; off>0; off>>=1){
        if (li < off){ s1[c]+=s1[c+off]; s2[c]+=s2[c+off]; }
        __syncthreads();
    }
    int base = c & ~63;
    float mu = s1[base]*(1.f/64.f);
    float var = s2[base]*(1.f/64.f) - mu*mu;
    float ht = (v-mu)*rsqrtf(var+1e-5f)*onw[c];
    float z = up[(size_t)row*512 + 256 + c];
    hs[(size_t)row*INNER_ + c] = (ht + skip[c]*xc[(size_t)row*INNER_+c]) * (z*fsigm(z));
}

// ---------------- sLSTM scan: 2 streams per wave, all 4 gates per lane ----------------
// Lane l: stream = l>>5 (batch pair share wave, same hh => same R), e = l&31.
// Each lane holds all four R gate-columns for its e (128 VGPRs); no cross-lane
// gate exchange. y broadcast within 32-lane groups via ds_swizzle (serves both
// streams with one instruction). No LDS, no barriers, no DS-latency shfl_xor.
#define SWZ_(D) yv[D] = __int_as_float(__builtin_amdgcn_ds_swizzle(yi, (D)<<5));
__global__ __launch_bounds__(64) void slstm_scan_wave2(
        const float* __restrict__ gx, const float* __restrict__ R,
        const float* __restrict__ bb, float* __restrict__ ys) {
    int blk = blockIdx.x;               // 16 blocks
    int hh = blk & 3; int grp = blk >> 2;
    int l = threadIdx.x;
    int half = l >> 5, e = l & 31;
    int b = grp*2 + half;
    float R0[32], R1[32], R2[32], R3[32];
    #pragma unroll
    for (int d = 0; d < 32; ++d) {
        const float* Rr = R + ((size_t)(hh*32 + d)*4)*32 + e;
        R0[d] = Rr[0]; R1[d] = Rr[32]; R2[d] = Rr[64]; R3[d] = Rr[96];
    }
    float bi = bb[(hh*4+0)*32+e], bf = bb[(hh*4+1)*32+e];
    float bz = bb[(hh*4+2)*32+e], bo = bb[(hh*4+3)*32+e];
    const float* gb_ = gx + (size_t)(b*S_)*512 + hh*128 + e;
    float* yb_ = ys + (size_t)(b*S_)*128 + hh*32 + e;
    float cst = 0.f, nst = 0.f, mst = 0.f, y = 0.f;
    float pi[2], pf[2], pz[2], po[2];
    #pragma unroll
    for (int u = 0; u < 2; ++u) {
        const float* p = gb_ + (size_t)u*512;
        pi[u]=p[0]; pf[u]=p[32]; pz[u]=p[64]; po[u]=p[96];
    }
    for (int t = 0; t < S_; t += 2) {
        float ni[2], nf[2], nz[2], no_[2];
        #pragma unroll
        for (int u = 0; u < 2; ++u) {
            int tn = t + 2 + u;
            const float* p = gb_ + (size_t)(tn < S_ ? tn : 0)*512;
            ni[u]=p[0]; nf[u]=p[32]; nz[u]=p[64]; no_[u]=p[96];
        }
        #pragma unroll
        for (int u = 0; u < 2; ++u) {
            int yi = __float_as_int(y);
            float yv[32];
            SWZ_(0)  SWZ_(1)  SWZ_(2)  SWZ_(3)  SWZ_(4)  SWZ_(5)  SWZ_(6)  SWZ_(7)
            SWZ_(8)  SWZ_(9)  SWZ_(10) SWZ_(11) SWZ_(12) SWZ_(13) SWZ_(14) SWZ_(15)
            SWZ_(16) SWZ_(17) SWZ_(18) SWZ_(19) SWZ_(20) SWZ_(21) SWZ_(22) SWZ_(23)
            SWZ_(24) SWZ_(25) SWZ_(26) SWZ_(27) SWZ_(28) SWZ_(29) SWZ_(30) SWZ_(31)
            float i0=0.f,i1=0.f,f0=0.f,f1=0.f,z0=0.f,z1=0.f,o0=0.f,o1=0.f;
            #pragma unroll
            for (int d = 0; d < 32; d += 2) {
                i0 += yv[d]*R0[d];   i1 += yv[d+1]*R0[d+1];
                f0 += yv[d]*R1[d];   f1 += yv[d+1]*R1[d+1];
                z0 += yv[d]*R2[d];   z1 += yv[d+1]*R2[d+1];
                o0 += yv[d]*R3[d];   o1 += yv[d+1]*R3[d+1];
            }
            float iraw = pi[u] + bi + (i0 + i1);
            float fraw = pf[u] + bf + (f0 + f1);
            float zraw = pz[u] + bz + (z0 + z1);
            float oraw = po[u] + bo + (o0 + o1);
            int t_abs = t + u;
            float lfm = mst + flogsig(fraw);
            float mnew = (t_abs == 0) ? iraw : fmaxf(iraw, lfm);
            float og = fsigm(oraw);
            float igv = __expf(iraw - mnew), fgv = __expf(lfm - mnew);
            cst = fgv*cst + igv*ftanh(zraw);
            nst = fgv*nst + igv;
            mst = mnew;
            y = og*cst*frcp(nst);
            yb_[(size_t)t_abs*128] = y;
        }
        #pragma unroll
        for (int u = 0; u < 2; ++u) { pi[u]=ni[u]; pf[u]=nf[u]; pz[u]=nz[u]; po[u]=no_[u]; }
    }
}

// ---------------- sLSTM out: h += mh_ln(ys; GS=32) * gnw ----------------
__global__ void slstm_addnorm(const float* __restrict__ ys, const float* __restrict__ w,
                              float* __restrict__ h) {
    int row = blockIdx.x; int c = threadIdx.x;  // 128
    float v = ys[(size_t)row*128 + c];
    __shared__ float s1[128], s2[128];
    s1[c]=v; s2[c]=v*v; __syncthreads();
    int li = c & 31;
    for (int off=16; off>0; off>>=1){
        if (li < off){ s1[c]+=s1[c+off]; s2[c]+=s2[c+off]; }
        __syncthreads();
    }
    int base = c & ~31;
    float mu = s1[base]*(1.f/32.f);
    float var = s2[base]*(1.f/32.f) - mu*mu;
    h[(size_t)row*128 + c] += (v-mu)*rsqrtf(var+1e-5f)*w[c];
}

// ---------------- FFN activation: gelu(g) * u2 ----------------
__global__ void ffn_act(const float* __restrict__ u, float* __restrict__ act) {
    int idx = blockIdx.x*blockDim.x + threadIdx.x;
    int total = MROWS_*192;
    if (idx >= total) return;
    int j = idx % 192; int m = idx / 192;
    float g  = u[(size_t)m*384 + j];
    float u2 = u[(size_t)m*384 + 192 + j];
    float ge = 0.5f*g*(1.0f + erff(g*0.70710678118f));
    act[(size_t)m*192 + j] = ge*u2;
}

// ---------------- Final FC on last token ----------------
__global__ void final_fc(const float* __restrict__ hp, const float* __restrict__ fcW,
                         const float* __restrict__ fcb, float* __restrict__ out) {
    int b = blockIdx.x; int lane = threadIdx.x;  // 64
    const float* r = hp + ((size_t)b*S_ + (S_-1))*128;
    float acc = r[lane]*fcW[lane] + r[lane+64]*fcW[lane+64];
    #pragma unroll
    for (int off=32; off>0; off>>=1) acc += __shfl_down(acc, off, 64);
    if (lane == 0) out[b] = acc + fcb[0];
}

extern "C" void kernel_launch(void* const* d_in, const int* in_sizes, int n_in,
                              void* d_out, int out_size, void* d_ws, size_t ws_size,
                              hipStream_t stream) {
    const float* x       = (const float*)d_in[0];
    const float* W_in    = (const float*)d_in[1];
    const float* b_in    = (const float*)d_in[2];
    const float* ln0_w   = (const float*)d_in[3];
    const float* m_Wup   = (const float*)d_in[4];
    const float* m_bup   = (const float*)d_in[5];
    const float* m_convk = (const float*)d_in[6];
    const float* m_convb = (const float*)d_in[7];
    const float* m_Wq    = (const float*)d_in[8];
    const float* m_bq    = (const float*)d_in[9];
    const float* m_Wk    = (const float*)d_in[10];
    const float* m_bk    = (const float*)d_in[11];
    const float* m_Wv    = (const float*)d_in[12];
    const float* m_bv    = (const float*)d_in[13];
    const float* m_Wig   = (const float*)d_in[14];
    const float* m_big   = (const float*)d_in[15];
    const float* m_Wfg   = (const float*)d_in[16];
    const float* m_bfg   = (const float*)d_in[17];
    const float* m_onw   = (const float*)d_in[18];
    const float* m_skip  = (const float*)d_in[19];
    const float* m_Wd    = (const float*)d_in[20];
    const float* m_bd    = (const float*)d_in[21];
    const float* ln1_w   = (const float*)d_in[22];
    const float* s_convk = (const float*)d_in[23];
    const float* s_convb = (const float*)d_in[24];
    const float* s_Wi    = (const float*)d_in[25];
    const float* s_Wf    = (const float*)d_in[26];
    const float* s_Wz    = (const float*)d_in[27];
    const float* s_Wo    = (const float*)d_in[28];
    const float* s_R     = (const float*)d_in[29];
    const float* s_b     = (const float*)d_in[30];
    const float* s_gnw   = (const float*)d_in[31];
    const float* ffn_nw  = (const float*)d_in[32];
    const float* f_Wu    = (const float*)d_in[33];
    const float* f_bu    = (const float*)d_in[34];
    const float* f_Wd    = (const float*)d_in[35];
    const float* f_bd    = (const float*)d_in[36];
    const float* post_w  = (const float*)d_in[37];
    const float* fc_W    = (const float*)d_in[38];
    const float* fc_b    = (const float*)d_in[39];
    float* out = (float*)d_out;

    float* W = (float*)d_ws;
    const size_t M1 = 1048576;        // 8192*128
    float* h    = W;                   // 1M
    float* r    = W + 1*M1;            // 1M
    float* up   = W + 2*M1;            // 4M
    float* xc   = W + 6*M1;            // 2M
    float* q    = W + 8*M1;            // 2M
    float* kbuf = W + 10*M1;           // 2M
    float* vbuf = W + 12*M1;           // 2M
    float* hc   = W + 14*M1;           // 2M
    float* igp  = W + 16*M1;
    float* fgp  = igp + 32768;
    float* lc   = fgp + 32768;
    float* av   = lc  + 32768;
    float* mx   = av  + 32768;
    float* hs   = q;
    float* gx   = kbuf;
    float* ys   = hc;
    float* rc   = xc;
    float* u    = up;
    float* act  = q;
    float* hp   = r;

    // 1. h = x @ W_in^T + b_in
    gemm_bias_big<<<dim3(128/64, MROWS_/64), 256, 0, stream>>>(x, W_in, b_in, nullptr, h, MROWS_, 128, F_);
    // 2. r = LN(h)*ln0_w
    ln_kernel<<<MROWS_, 128, 0, stream>>>(h, ln0_w, r);
    // 3. up = r @ m_Wup^T + m_bup
    gemm_bias_big<<<dim3(512/64, MROWS_/64), 256, 0, stream>>>(r, m_Wup, m_bup, nullptr, up, MROWS_, 512, 128);
    // 4. xc = silu(causal_conv(xm))
    conv_silu<<<(MROWS_*256)/256, 256, 0, stream>>>(up, 512, m_convk, m_convb, xc, 256, 256);
    // 5. q,k,v headwise
    headwise4<<<(MROWS_*256)/256, 256, 0, stream>>>(xc, 256, m_Wq, m_bq, q);
    headwise4<<<(MROWS_*256)/256, 256, 0, stream>>>(xc, 256, m_Wk, m_bk, kbuf);
    headwise4<<<(MROWS_*256)/256, 256, 0, stream>>>(up, 512, m_Wv, m_bv, vbuf);
    // 6. ig/fg projections
    gateproj<<<MROWS_, 64, 0, stream>>>(q, kbuf, vbuf, m_Wig, m_big, m_Wfg, m_bfg, igp, fgp);
    // 7. decay precompute
    mlstm_scan_pre<<<B_*NH_, 1024, 0, stream>>>(igp, fgp, lc, av, mx);
    // 8. attention (tiled)
    mlstm_attn_tiled<<<B_*NH_*16, 256, 0, stream>>>(q, kbuf, vbuf, lc, av, mx, hc);
    // 9. multihead LN + skip + gate
    mlstm_out<<<MROWS_, 256, 0, stream>>>(hc, xc, up, m_onw, m_skip, hs);
    // 10. h += hs @ m_Wd^T + m_bd
    gemm_bias_big<<<dim3(128/64, MROWS_/64), 256, 0, stream>>>(hs, m_Wd, m_bd, h, h, MROWS_, 128, 256);
    // 11. r = LN(h)*ln1_w
    ln_kernel<<<MROWS_, 128, 0, stream>>>(h, ln1_w, r);
    // 12. rc = silu(causal_conv(r))
    conv_silu<<<(MROWS_*128)/256, 256, 0, stream>>>(r, 128, s_convk, s_convb, rc, 128, 128);
    // 13. sLSTM gates (all 4 in one launch)
    slstm_gates<<<(MROWS_*128)/256, 256, 0, stream>>>(rc, r, s_Wi, s_Wf, s_Wz, s_Wo, gx);
    // 14. sequential scan (2 streams per wave, swizzle broadcast)
    slstm_scan_wave2<<<16, 64, 0, stream>>>(gx, s_R, s_b, ys);
    // 15. h += mh_ln(ys)*s_gnw
    slstm_addnorm<<<MROWS_, 128, 0, stream>>>(ys, s_gnw, h);
    // 16. r = LN(h)*ffn_nw
    ln_kernel<<<MROWS_, 128, 0, stream>>>(h, ffn_nw, r);
    // 17. u = r @ f_Wu^T + f_bu
    gemm_bias_big<<<dim3(384/64, MROWS_/64), 256, 0, stream>>>(r, f_Wu, f_bu, nullptr, u, MROWS_, 384, 128);
    // 18. act = gelu(g)*u2
    ffn_act<<<(MROWS_*192)/256, 256, 0, stream>>>(u, act);
    // 19. h += act @ f_Wd^T + f_bd
    gemm_bias_big<<<dim3(128/64, MROWS_/64), 256, 0, stream>>>(act, f_Wd, f_bd, h, h, MROWS_, 128, 192);
    // 20. hp = LN(h)*post_w
    ln_kernel<<<MROWS_, 128, 0, stream>>>(h, post_w, hp);
    // 21. out = hp[:, -1, :] @ fc_W^T + fc_b
    final_fc<<<B_, 64, 0, stream>>>(hp, fc_W, fc_b, out);
    (void)in_sizes; (void)n_in; (void)out_size; (void)ws_size;
}

// Round 8
// 1032.797 us; speedup vs baseline: 1.2192x; 1.2192x over previous
//
#include <hip/hip_runtime.h>
#include <hip/hip_bf16.h>
#include <math.h>

#define B_ 8
#define S_ 1024
#define F_ 75
#define D_ 128
#define INNER_ 256
#define NH_ 4
#define DH_ 64
#define MROWS_ (B_*S_)   // 8192

static __device__ __forceinline__ float frcp(float x){ return __builtin_amdgcn_rcpf(x); }
static __device__ __forceinline__ float fsigm(float x){ return frcp(1.0f + __expf(-x)); }
static __device__ __forceinline__ float flogsig(float x){
    return fminf(x, 0.f) - __logf(1.0f + __expf(-fabsf(x)));
}
static __device__ __forceinline__ float ftanh(float z){
    return 1.0f - 2.0f*frcp(__expf(2.0f*z) + 1.0f);
}

// ---------------- Tiled GEMM: C = A @ W^T + bias (+ res) ----------------
__global__ __launch_bounds__(256, 2) void gemm_bias_big(
        const float* __restrict__ A, const float* __restrict__ W,
        const float* __restrict__ bias, const float* __restrict__ res,
        float* __restrict__ C, int M, int N, int K) {
    __shared__ float As[64*68];
    __shared__ float Ws[64*68];
    int tid = threadIdx.x;
    int wid = tid >> 6, lane = tid & 63;
    int wy = wid >> 1, wx = wid & 1;
    int sg = lane >> 3, tg = lane & 7;
    int m0 = blockIdx.y*64, n0 = blockIdx.x*64;
    int r = tid >> 2, c0 = (tid & 3) << 4;
    bool vec = ((K & 3) == 0);
    float acc[4][4];
    #pragma unroll
    for (int i = 0; i < 4; ++i)
        #pragma unroll
        for (int j = 0; j < 4; ++j) acc[i][j] = 0.f;

    for (int k0 = 0; k0 < K; k0 += 64) {
        __syncthreads();
        const float* Ar = A + (size_t)(m0+r)*K + k0;
        const float* Wr = W + (size_t)(n0+r)*K + k0;
        if (vec) {
            #pragma unroll
            for (int i = 0; i < 4; ++i) {
                *(float4*)(&As[r*68 + c0 + 4*i]) = *(const float4*)(Ar + c0 + 4*i);
                *(float4*)(&Ws[r*68 + c0 + 4*i]) = *(const float4*)(Wr + c0 + 4*i);
            }
        } else {
            #pragma unroll
            for (int i = 0; i < 4; ++i)
                #pragma unroll
                for (int e = 0; e < 4; ++e) {
                    int c = c0 + 4*i + e;
                    bool ok = (k0 + c) < K;
                    As[r*68 + c] = ok ? Ar[c] : 0.f;
                    Ws[r*68 + c] = ok ? Wr[c] : 0.f;
                }
        }
        __syncthreads();
        const float* arow = &As[(32*wy + sg)*68];
        const float* brow = &Ws[(32*wx + tg)*68];
        #pragma unroll 2
        for (int d = 0; d < 64; d += 4) {
            float4 b0 = *(const float4*)(brow + 0*544 + d);
            float4 b1 = *(const float4*)(brow + 1*544 + d);
            float4 b2 = *(const float4*)(brow + 2*544 + d);
            float4 b3 = *(const float4*)(brow + 3*544 + d);
            #pragma unroll
            for (int i = 0; i < 4; ++i) {
                float4 a = *(const float4*)(arow + i*544 + d);
                acc[i][0] += a.x*b0.x + a.y*b0.y + a.z*b0.z + a.w*b0.w;
                acc[i][1] += a.x*b1.x + a.y*b1.y + a.z*b1.z + a.w*b1.w;
                acc[i][2] += a.x*b2.x + a.y*b2.y + a.z*b2.z + a.w*b2.w;
                acc[i][3] += a.x*b3.x + a.y*b3.y + a.z*b3.z + a.w*b3.w;
            }
        }
    }
    #pragma unroll
    for (int i = 0; i < 4; ++i) {
        int m = m0 + 32*wy + 8*i + sg;
        #pragma unroll
        for (int j = 0; j < 4; ++j) {
            int n = n0 + 32*wx + 8*j + tg;
            float v = acc[i][j] + bias[n];
            if (res) v += res[(size_t)m*N + n];
            C[(size_t)m*N + n] = v;
        }
    }
}

// ---------------- Plain LayerNorm over D=128 ----------------
__global__ void ln_kernel(const float* __restrict__ X, const float* __restrict__ w,
                          float* __restrict__ Y) {
    int row = blockIdx.x, t = threadIdx.x;  // 128 threads
    float v = X[(size_t)row*128 + t];
    __shared__ float s1[128], s2[128];
    s1[t]=v; s2[t]=v*v; __syncthreads();
    for (int off=64; off>0; off>>=1){
        if (t<off){ s1[t]+=s1[t+off]; s2[t]+=s2[t+off]; }
        __syncthreads();
    }
    float mu = s1[0]*(1.f/128.f);
    float var = s2[0]*(1.f/128.f) - mu*mu;
    Y[(size_t)row*128 + t] = (v-mu)*rsqrtf(var+1e-5f)*w[t];
}

// ---------------- Causal depthwise conv (K=4) + SiLU ----------------
__global__ void conv_silu(const float* __restrict__ X, int ldx,
                          const float* __restrict__ kw, const float* __restrict__ kb,
                          float* __restrict__ Y, int ldy, int C) {
    int idx = blockIdx.x*blockDim.x + threadIdx.x;
    int total = MROWS_*C;
    if (idx >= total) return;
    int c = idx % C; int bs = idx / C;
    int s = bs % S_; int b = bs / S_;
    float acc = kb[c];
    #pragma unroll
    for (int i = 0; i < 4; ++i) {
        int sp = s - 3 + i;
        if (sp >= 0) acc += X[((size_t)b*S_+sp)*ldx + c] * kw[c*4+i];
    }
    Y[((size_t)b*S_+s)*ldy + c] = acc * fsigm(acc);
}

// ---------------- Headwise block-diagonal proj (mLSTM q/k/v, HS=4) ----------------
__global__ void headwise4(const float* __restrict__ X, int ldx,
                          const float* __restrict__ W, const float* __restrict__ bias,
                          float* __restrict__ Y) {
    int idx = blockIdx.x*blockDim.x + threadIdx.x;
    int total = MROWS_*INNER_;
    if (idx >= total) return;
    int co = idx % INNER_; int bs = idx / INNER_;
    int h = co >> 2, o = co & 3;
    const float* Wh = W + ((size_t)h*4 + o)*4;
    const float* xr = X + (size_t)bs*ldx + h*4;
    float acc = bias[co];
    #pragma unroll
    for (int i = 0; i < 4; ++i) acc += xr[i]*Wh[i];
    Y[(size_t)bs*INNER_ + co] = acc;
}

// ---------------- sLSTM all-4-gates headwise (HS=32) ----------------
__global__ void slstm_gates(const float* __restrict__ rc, const float* __restrict__ r,
                            const float* __restrict__ Wi, const float* __restrict__ Wf,
                            const float* __restrict__ Wz, const float* __restrict__ Wo,
                            float* __restrict__ GX) {
    int idx = blockIdx.x*blockDim.x + threadIdx.x;
    int total = MROWS_*128;
    if (idx >= total) return;
    int co = idx % 128; int bs = idx / 128;
    int h = co >> 5, o = co & 31;
    size_t wb = ((size_t)h*32 + o)*32;
    const float* xc_ = rc + (size_t)bs*128 + h*32;
    const float* xr_ = r  + (size_t)bs*128 + h*32;
    float di=0.f, df=0.f, dz=0.f, doo=0.f;
    #pragma unroll
    for (int i = 0; i < 32; ++i) {
        float a = xc_[i], c = xr_[i];
        di  += a*Wi[wb+i];
        df  += a*Wf[wb+i];
        dz  += c*Wz[wb+i];
        doo += c*Wo[wb+i];
    }
    float* g = GX + (size_t)bs*512 + h*128 + o;
    g[0]  = di;
    g[32] = df;
    g[64] = dz;
    g[96] = doo;
}

// ---------------- ig/fg gate projection over concat(q,k,v) ----------------
__global__ void gateproj(const float* __restrict__ q, const float* __restrict__ k,
                         const float* __restrict__ v,
                         const float* __restrict__ Wig, const float* __restrict__ big,
                         const float* __restrict__ Wfg, const float* __restrict__ bfg,
                         float* __restrict__ igp, float* __restrict__ fgp) {
    int bs = blockIdx.x; int lane = threadIdx.x;  // 64 threads
    int b = bs / S_, s = bs % S_;
    const float* qr = q + (size_t)bs*INNER_;
    const float* kr = k + (size_t)bs*INNER_;
    const float* vr = v + (size_t)bs*INNER_;
    float dots[8];
    #pragma unroll
    for (int g=0; g<8; ++g) dots[g]=0.f;
    for (int c = lane; c < INNER_; c += 64) {
        float qv = qr[c], kv = kr[c], vv = vr[c];
        #pragma unroll
        for (int g=0; g<4; ++g) {
            dots[g]   += qv*Wig[g*768+c] + kv*Wig[g*768+256+c] + vv*Wig[g*768+512+c];
            dots[4+g] += qv*Wfg[g*768+c] + kv*Wfg[g*768+256+c] + vv*Wfg[g*768+512+c];
        }
    }
    #pragma unroll
    for (int off=32; off>0; off>>=1)
        #pragma unroll
        for (int g=0; g<8; ++g) dots[g] += __shfl_down(dots[g], off, 64);
    if (lane == 0) {
        #pragma unroll
        for (int g=0; g<4; ++g) {
            igp[((size_t)b*NH_+g)*S_ + s] = dots[g]   + big[g];
            fgp[((size_t)b*NH_+g)*S_ + s] = dots[4+g] + bfg[g];
        }
    }
}

// ---------------- mLSTM decay precompute ----------------
__global__ void mlstm_scan_pre(const float* __restrict__ igp, const float* __restrict__ fgp,
                               float* __restrict__ lc, float* __restrict__ av,
                               float* __restrict__ mx) {
    int bh = blockIdx.x; int t = threadIdx.x;  // 1024 threads
    __shared__ float buf[2][1024];
    float ls = flogsig(fgp[(size_t)bh*S_ + t]);
    int cur = 0;
    buf[0][t] = ls; __syncthreads();
    for (int off=1; off<1024; off<<=1) {
        float x2 = buf[cur][t];
        if (t >= off) x2 += buf[cur][t-off];
        buf[cur^1][t] = x2; cur ^= 1; __syncthreads();
    }
    float lcv = buf[cur][t];
    lc[(size_t)bh*S_+t] = lcv;
    float a = igp[(size_t)bh*S_+t] - lcv;
    av[(size_t)bh*S_+t] = a;
    __syncthreads();
    cur = 0; buf[0][t] = a; __syncthreads();
    for (int off=1; off<1024; off<<=1) {
        float x2 = buf[cur][t];
        if (t >= off) x2 = fmaxf(x2, buf[cur][t-off]);
        buf[cur^1][t] = x2; cur ^= 1; __syncthreads();
    }
    mx[(size_t)bh*S_+t] = buf[cur][t];
}

// ---------------- mLSTM attention: tiled flash-style ----------------
__global__ __launch_bounds__(256, 2) void mlstm_attn_tiled(
        const float* __restrict__ q, const float* __restrict__ k,
        const float* __restrict__ v, const float* __restrict__ lc,
        const float* __restrict__ av, const float* __restrict__ mx,
        float* __restrict__ hc) {
    int bid = blockIdx.x;
    int stile = 15 - (bid & 15);
    int bh = bid >> 4;
    int hh = bh & 3, b = bh >> 2;
    int s0 = stile << 6;
    int tid = threadIdx.x;
    int wid = tid >> 6, lane = tid & 63;
    int wy = wid >> 1, wx = wid & 1;
    int sg = lane >> 3, tg = lane & 7;

    __shared__ float qs[64*68];
    __shared__ float kst[64*68];
    __shared__ float vtT[64*68];
    __shared__ float avt[64], maxsL[64], normL[64], rsumL[128];

    const size_t bhS = (size_t)bh * S_;
    {
        int r = tid >> 2, c0 = (tid & 3) << 4;
        const float* qg = q + ((size_t)(b*S_) + s0 + r)*INNER_ + hh*64;
        #pragma unroll
        for (int i = 0; i < 4; ++i) {
            float4 t4 = *(const float4*)(qg + c0 + 4*i);
            float4 w4; w4.x=t4.x*0.125f; w4.y=t4.y*0.125f; w4.z=t4.z*0.125f; w4.w=t4.w*0.125f;
            *(float4*)(&qs[r*68 + c0 + 4*i]) = w4;
        }
        if (tid < 64) maxsL[tid] = lc[bhS + s0 + tid] + mx[bhS + s0 + tid];
    }
    float msv[4];
    #pragma unroll
    for (int i = 0; i < 4; ++i)
        msv[i] = mx[bhS + s0 + 32*wy + 8*i + sg];

    float O[4][4];
    float rsAcc[4];
    #pragma unroll
    for (int i = 0; i < 4; ++i) {
        rsAcc[i] = 0.f;
        #pragma unroll
        for (int j = 0; j < 4; ++j) O[i][j] = 0.f;
    }

    for (int t0 = 0; t0 <= s0; t0 += 64) {
        __syncthreads();
        {
            int r = tid >> 2, c0 = (tid & 3) << 4;
            const float* kg = k + ((size_t)(b*S_) + t0 + r)*INNER_ + hh*64;
            const float* vg = v + ((size_t)(b*S_) + t0 + r)*INNER_ + hh*64;
            #pragma unroll
            for (int i = 0; i < 4; ++i) {
                *(float4*)(&kst[r*68 + c0 + 4*i]) = *(const float4*)(kg + c0 + 4*i);
                float4 v4 = *(const float4*)(vg + c0 + 4*i);
                int dc = c0 + 4*i;
                vtT[(dc+0)*68 + r] = v4.x;
                vtT[(dc+1)*68 + r] = v4.y;
                vtT[(dc+2)*68 + r] = v4.z;
                vtT[(dc+3)*68 + r] = v4.w;
            }
            if (tid < 64) avt[tid] = av[bhS + t0 + tid];
        }
        __syncthreads();
        float dot[4][4];
        #pragma unroll
        for (int i = 0; i < 4; ++i)
            #pragma unroll
            for (int j = 0; j < 4; ++j) dot[i][j] = 0.f;
        {
            const float* qrow = &qs[(32*wy + sg)*68];
            const float* krow = &kst[(32*wx + tg)*68];
            #pragma unroll 2
            for (int d = 0; d < 64; d += 4) {
                float4 b0 = *(const float4*)(krow + 0*544 + d);
                float4 b1 = *(const float4*)(krow + 1*544 + d);
                float4 b2 = *(const float4*)(krow + 2*544 + d);
                float4 b3 = *(const float4*)(krow + 3*544 + d);
                #pragma unroll
                for (int i = 0; i < 4; ++i) {
                    float4 a = *(const float4*)(qrow + i*544 + d);
                    dot[i][0] += a.x*b0.x + a.y*b0.y + a.z*b0.z + a.w*b0.w;
                    dot[i][1] += a.x*b1.x + a.y*b1.y + a.z*b1.z + a.w*b1.w;
                    dot[i][2] += a.x*b2.x + a.y*b2.y + a.z*b2.z + a.w*b2.w;
                    dot[i][3] += a.x*b3.x + a.y*b3.y + a.z*b3.z + a.w*b3.w;
                }
            }
        }
        __syncthreads();
        #pragma unroll
        for (int i = 0; i < 4; ++i) {
            int s_loc = 32*wy + 8*i + sg;
            float rp = 0.f;
            #pragma unroll
            for (int j = 0; j < 4; ++j) {
                int t_loc = 32*wx + 8*j + tg;
                bool ok = (t0 + t_loc) <= (s0 + s_loc);
                float p = ok ? dot[i][j]*__expf(avt[t_loc] - msv[i]) : 0.f;
                kst[s_loc*68 + t_loc] = p;
                rp += p;
            }
            rp += __shfl_xor(rp, 1);
            rp += __shfl_xor(rp, 2);
            rp += __shfl_xor(rp, 4);
            rsAcc[i] += rp;
        }
        __syncthreads();
        {
            const float* prow = &kst[(32*wy + sg)*68];
            const float* vrow = &vtT[(32*wx + tg)*68];
            #pragma unroll 2
            for (int tt = 0; tt < 64; tt += 4) {
                float4 b0 = *(const float4*)(vrow + 0*544 + tt);
                float4 b1 = *(const float4*)(vrow + 1*544 + tt);
                float4 b2 = *(const float4*)(vrow + 2*544 + tt);
                float4 b3 = *(const float4*)(vrow + 3*544 + tt);
                #pragma unroll
                for (int i = 0; i < 4; ++i) {
                    float4 a = *(const float4*)(prow + i*544 + tt);
                    O[i][0] += a.x*b0.x + a.y*b0.y + a.z*b0.z + a.w*b0.w;
                    O[i][1] += a.x*b1.x + a.y*b1.y + a.z*b1.z + a.w*b1.w;
                    O[i][2] += a.x*b2.x + a.y*b2.y + a.z*b2.z + a.w*b2.w;
                    O[i][3] += a.x*b3.x + a.y*b3.y + a.z*b3.z + a.w*b3.w;
                }
            }
        }
    }
    if (tg == 0) {
        #pragma unroll
        for (int i = 0; i < 4; ++i)
            rsumL[wx*64 + 32*wy + 8*i + sg] = rsAcc[i];
    }
    __syncthreads();
    if (tid < 64) {
        float tot = rsumL[tid] + rsumL[64 + tid];
        normL[tid] = fmaxf(fabsf(tot), __expf(-maxsL[tid])) + 1e-6f;
    }
    __syncthreads();
    #pragma unroll
    for (int i = 0; i < 4; ++i) {
        int s_loc = 32*wy + 8*i + sg;
        float inv = 1.0f / normL[s_loc];
        #pragma unroll
        for (int j = 0; j < 4; ++j) {
            int d_loc = 32*wx + 8*j + tg;
            hc[((size_t)(b*S_) + s0 + s_loc)*INNER_ + hh*64 + d_loc] = O[i][j] * inv;
        }
    }
}

// ---------------- mLSTM output: multihead LN (GS=64) + skip + gate ----------------
__global__ void mlstm_out(const float* __restrict__ hc, const float* __restrict__ xc,
                          const float* __restrict__ up, const float* __restrict__ onw,
                          const float* __restrict__ skip, float* __restrict__ hs) {
    int row = blockIdx.x; int c = threadIdx.x;  // 256 threads
    float v = hc[(size_t)row*INNER_ + c];
    __shared__ float s1[256], s2[256];
    s1[c]=v; s2[c]=v*v; __syncthreads();
    int li = c & 63;
    for (int off=32; off>0; off>>=1){
        if (li < off){ s1[c]+=s1[c+off]; s2[c]+=s2[c+off]; }
        __syncthreads();
    }
    int base = c & ~63;
    float mu = s1[base]*(1.f/64.f);
    float var = s2[base]*(1.f/64.f) - mu*mu;
    float ht = (v-mu)*rsqrtf(var+1e-5f)*onw[c];
    float z = up[(size_t)row*512 + 256 + c];
    hs[(size_t)row*INNER_ + c] = (ht + skip[c]*xc[(size_t)row*INNER_+c]) * (z*fsigm(z));
}

// ---------------- sLSTM scan: ONE WAVE per (b,h), R in regs, readlane bcast ----------------
// __launch_bounds__(64, 1): min 1 wave/EU -> VGPR budget ~512, so the RA keeps
// Rc0/Rc1 resident instead of rematerializing the loads inside the t-loop
// (round-6 profile showed VGPR_Count=52 < the 64 live R values -> in-loop reloads).
__global__ __launch_bounds__(64, 1) void slstm_scan_wave(
        const float* __restrict__ gx, const float* __restrict__ R,
        const float* __restrict__ bb, float* __restrict__ ys) {
    int blk = blockIdx.x; int hh = blk & 3; int b = blk >> 2;
    int l = threadIdx.x;  // 0..63
    float Rc0[32], Rc1[32];
    #pragma unroll
    for (int d = 0; d < 32; ++d) {
        Rc0[d] = R[(size_t)(hh*32 + d)*128 + l];
        Rc1[d] = R[(size_t)(hh*32 + d)*128 + l + 64];
    }
    float bj0 = bb[hh*128 + l], bj1 = bb[hh*128 + l + 64];
    float cst = 0.f, nst = 0.f, mst = 0.f, y = 0.f;
    const float* gbase = gx + (size_t)(b*S_)*512 + hh*128;
    float* ybase = ys + (size_t)(b*S_)*128 + hh*32;
    float ga[4], gb[4];
    #pragma unroll
    for (int u = 0; u < 4; ++u) {
        ga[u] = gbase[(size_t)u*512 + l];
        gb[u] = gbase[(size_t)u*512 + l + 64];
    }
    for (int t = 0; t < S_; t += 4) {
        float gna[4], gnb[4];
        #pragma unroll
        for (int u = 0; u < 4; ++u) {
            int tn = t + 4 + u;
            size_t off = (size_t)(tn < S_ ? tn : 0) * 512;
            gna[u] = gbase[off + l];
            gnb[u] = gbase[off + l + 64];
        }
        #pragma unroll
        for (int u = 0; u < 4; ++u) {
            float r0 = ga[u] + bj0;
            float r1 = gb[u] + bj1;
            #pragma unroll
            for (int d = 0; d < 32; ++d) {
                float yd = __int_as_float(__builtin_amdgcn_readlane(__float_as_int(y), d));
                r0 += yd * Rc0[d];
                r1 += yd * Rc1[d];
            }
            float fo0 = __shfl_xor(r0, 32, 64);
            float fo1 = __shfl_xor(r1, 32, 64);
            int t_abs = t + u;
            float iraw = r0, zraw = r1, fraw = fo0, oraw = fo1;
            float lfm = mst + flogsig(fraw);
            float mnew = (t_abs == 0) ? iraw : fmaxf(iraw, lfm);
            float og = fsigm(oraw);
            float igv = __expf(iraw - mnew), fgv = __expf(lfm - mnew);
            cst = fgv*cst + igv*ftanh(zraw);
            nst = fgv*nst + igv;
            mst = mnew;
            y = og*cst*frcp(nst);
            if (l < 32) ybase[(size_t)t_abs*128 + l] = y;
        }
        #pragma unroll
        for (int u = 0; u < 4; ++u) { ga[u] = gna[u]; gb[u] = gnb[u]; }
    }
}

// ---------------- sLSTM out: h += mh_ln(ys; GS=32) * gnw ----------------
__global__ void slstm_addnorm(const float* __restrict__ ys, const float* __restrict__ w,
                              float* __restrict__ h) {
    int row = blockIdx.x; int c = threadIdx.x;  // 128
    float v = ys[(size_t)row*128 + c];
    __shared__ float s1[128], s2[128];
    s1[c]=v; s2[c]=v*v; __syncthreads();
    int li = c & 31;
    for (int off=16; off>0; off>>=1){
        if (li < off){ s1[c]+=s1[c+off]; s2[c]+=s2[c+off]; }
        __syncthreads();
    }
    int base = c & ~31;
    float mu = s1[base]*(1.f/32.f);
    float var = s2[base]*(1.f/32.f) - mu*mu;
    h[(size_t)row*128 + c] += (v-mu)*rsqrtf(var+1e-5f)*w[c];
}

// ---------------- FFN activation: gelu(g) * u2 ----------------
__global__ void ffn_act(const float* __restrict__ u, float* __restrict__ act) {
    int idx = blockIdx.x*blockDim.x + threadIdx.x;
    int total = MROWS_*192;
    if (idx >= total) return;
    int j = idx % 192; int m = idx / 192;
    float g  = u[(size_t)m*384 + j];
    float u2 = u[(size_t)m*384 + 192 + j];
    float ge = 0.5f*g*(1.0f + erff(g*0.70710678118f));
    act[(size_t)m*192 + j] = ge*u2;
}

// ---------------- Final FC on last token ----------------
__global__ void final_fc(const float* __restrict__ hp, const float* __restrict__ fcW,
                         const float* __restrict__ fcb, float* __restrict__ out) {
    int b = blockIdx.x; int lane = threadIdx.x;  // 64
    const float* r = hp + ((size_t)b*S_ + (S_-1))*128;
    float acc = r[lane]*fcW[lane] + r[lane+64]*fcW[lane+64];
    #pragma unroll
    for (int off=32; off>0; off>>=1) acc += __shfl_down(acc, off, 64);
    if (lane == 0) out[b] = acc + fcb[0];
}

extern "C" void kernel_launch(void* const* d_in, const int* in_sizes, int n_in,
                              void* d_out, int out_size, void* d_ws, size_t ws_size,
                              hipStream_t stream) {
    const float* x       = (const float*)d_in[0];
    const float* W_in    = (const float*)d_in[1];
    const float* b_in    = (const float*)d_in[2];
    const float* ln0_w   = (const float*)d_in[3];
    const float* m_Wup   = (const float*)d_in[4];
    const float* m_bup   = (const float*)d_in[5];
    const float* m_convk = (const float*)d_in[6];
    const float* m_convb = (const float*)d_in[7];
    const float* m_Wq    = (const float*)d_in[8];
    const float* m_bq    = (const float*)d_in[9];
    const float* m_Wk    = (const float*)d_in[10];
    const float* m_bk    = (const float*)d_in[11];
    const float* m_Wv    = (const float*)d_in[12];
    const float* m_bv    = (const float*)d_in[13];
    const float* m_Wig   = (const float*)d_in[14];
    const float* m_big   = (const float*)d_in[15];
    const float* m_Wfg   = (const float*)d_in[16];
    const float* m_bfg   = (const float*)d_in[17];
    const float* m_onw   = (const float*)d_in[18];
    const float* m_skip  = (const float*)d_in[19];
    const float* m_Wd    = (const float*)d_in[20];
    const float* m_bd    = (const float*)d_in[21];
    const float* ln1_w   = (const float*)d_in[22];
    const float* s_convk = (const float*)d_in[23];
    const float* s_convb = (const float*)d_in[24];
    const float* s_Wi    = (const float*)d_in[25];
    const float* s_Wf    = (const float*)d_in[26];
    const float* s_Wz    = (const float*)d_in[27];
    const float* s_Wo    = (const float*)d_in[28];
    const float* s_R     = (const float*)d_in[29];
    const float* s_b     = (const float*)d_in[30];
    const float* s_gnw   = (const float*)d_in[31];
    const float* ffn_nw  = (const float*)d_in[32];
    const float* f_Wu    = (const float*)d_in[33];
    const float* f_bu    = (const float*)d_in[34];
    const float* f_Wd    = (const float*)d_in[35];
    const float* f_bd    = (const float*)d_in[36];
    const float* post_w  = (const float*)d_in[37];
    const float* fc_W    = (const float*)d_in[38];
    const float* fc_b    = (const float*)d_in[39];
    float* out = (float*)d_out;

    float* W = (float*)d_ws;
    const size_t M1 = 1048576;        // 8192*128
    float* h    = W;                   // 1M
    float* r    = W + 1*M1;            // 1M
    float* up   = W + 2*M1;            // 4M
    float* xc   = W + 6*M1;            // 2M
    float* q    = W + 8*M1;            // 2M
    float* kbuf = W + 10*M1;           // 2M
    float* vbuf = W + 12*M1;           // 2M
    float* hc   = W + 14*M1;           // 2M
    float* igp  = W + 16*M1;
    float* fgp  = igp + 32768;
    float* lc   = fgp + 32768;
    float* av   = lc  + 32768;
    float* mx   = av  + 32768;
    float* hs   = q;
    float* gx   = kbuf;
    float* ys   = hc;
    float* rc   = xc;
    float* u    = up;
    float* act  = q;
    float* hp   = r;

    // 1. h = x @ W_in^T + b_in
    gemm_bias_big<<<dim3(128/64, MROWS_/64), 256, 0, stream>>>(x, W_in, b_in, nullptr, h, MROWS_, 128, F_);
    // 2. r = LN(h)*ln0_w
    ln_kernel<<<MROWS_, 128, 0, stream>>>(h, ln0_w, r);
    // 3. up = r @ m_Wup^T + m_bup
    gemm_bias_big<<<dim3(512/64, MROWS_/64), 256, 0, stream>>>(r, m_Wup, m_bup, nullptr, up, MROWS_, 512, 128);
    // 4. xc = silu(causal_conv(xm))
    conv_silu<<<(MROWS_*256)/256, 256, 0, stream>>>(up, 512, m_convk, m_convb, xc, 256, 256);
    // 5. q,k,v headwise
    headwise4<<<(MROWS_*256)/256, 256, 0, stream>>>(xc, 256, m_Wq, m_bq, q);
    headwise4<<<(MROWS_*256)/256, 256, 0, stream>>>(xc, 256, m_Wk, m_bk, kbuf);
    headwise4<<<(MROWS_*256)/256, 256, 0, stream>>>(up, 512, m_Wv, m_bv, vbuf);
    // 6. ig/fg projections
    gateproj<<<MROWS_, 64, 0, stream>>>(q, kbuf, vbuf, m_Wig, m_big, m_Wfg, m_bfg, igp, fgp);
    // 7. decay precompute
    mlstm_scan_pre<<<B_*NH_, 1024, 0, stream>>>(igp, fgp, lc, av, mx);
    // 8. attention (tiled)
    mlstm_attn_tiled<<<B_*NH_*16, 256, 0, stream>>>(q, kbuf, vbuf, lc, av, mx, hc);
    // 9. multihead LN + skip + gate
    mlstm_out<<<MROWS_, 256, 0, stream>>>(hc, xc, up, m_onw, m_skip, hs);
    // 10. h += hs @ m_Wd^T + m_bd
    gemm_bias_big<<<dim3(128/64, MROWS_/64), 256, 0, stream>>>(hs, m_Wd, m_bd, h, h, MROWS_, 128, 256);
    // 11. r = LN(h)*ln1_w
    ln_kernel<<<MROWS_, 128, 0, stream>>>(h, ln1_w, r);
    // 12. rc = silu(causal_conv(r))
    conv_silu<<<(MROWS_*128)/256, 256, 0, stream>>>(r, 128, s_convk, s_convb, rc, 128, 128);
    // 13. sLSTM gates (all 4 in one launch)
    slstm_gates<<<(MROWS_*128)/256, 256, 0, stream>>>(rc, r, s_Wi, s_Wf, s_Wz, s_Wo, gx);
    // 14. sequential scan (single wave per (b,h), launch_bounds(64,1))
    slstm_scan_wave<<<B_*NH_, 64, 0, stream>>>(gx, s_R, s_b, ys);
    // 15. h += mh_ln(ys)*s_gnw
    slstm_addnorm<<<MROWS_, 128, 0, stream>>>(ys, s_gnw, h);
    // 16. r = LN(h)*ffn_nw
    ln_kernel<<<MROWS_, 128, 0, stream>>>(h, ffn_nw, r);
    // 17. u = r @ f_Wu^T + f_bu
    gemm_bias_big<<<dim3(384/64, MROWS_/64), 256, 0, stream>>>(r, f_Wu, f_bu, nullptr, u, MROWS_, 384, 128);
    // 18. act = gelu(g)*u2
    ffn_act<<<(MROWS_*192)/256, 256, 0, stream>>>(u, act);
    // 19. h += act @ f_Wd^T + f_bd
    gemm_bias_big<<<dim3(128/64, MROWS_/64), 256, 0, stream>>>(act, f_Wd, f_bd, h, h, MROWS_, 128, 192);
    // 20. hp = LN(h)*post_w
    ln_kernel<<<MROWS_, 128, 0, stream>>>(h, post_w, hp);
    // 21. out = hp[:, -1, :] @ fc_W^T + fc_b
    final_fc<<<B_, 64, 0, stream>>>(hp, fc_W, fc_b, out);
    (void)in_sizes; (void)n_in; (void)out_size; (void)ws_size;
}

// Round 9
// 985.281 us; speedup vs baseline: 1.2780x; 1.0482x over previous
//
#include <hip/hip_runtime.h>
#include <hip/hip_bf16.h>
#include <math.h>

#define B_ 8
#define S_ 1024
#define F_ 75
#define D_ 128
#define INNER_ 256
#define NH_ 4
#define DH_ 64
#define MROWS_ (B_*S_)   // 8192

static __device__ __forceinline__ float frcp(float x){ return __builtin_amdgcn_rcpf(x); }
static __device__ __forceinline__ float fsigm(float x){ return frcp(1.0f + __expf(-x)); }
static __device__ __forceinline__ float flogsig(float x){
    return fminf(x, 0.f) - __logf(1.0f + __expf(-fabsf(x)));
}
static __device__ __forceinline__ float ftanh(float z){
    return 1.0f - 2.0f*frcp(__expf(2.0f*z) + 1.0f);
}

// ---------------- Tiled GEMM: C = A @ W^T + bias (+ res) ----------------
__global__ __launch_bounds__(256, 2) void gemm_bias_big(
        const float* __restrict__ A, const float* __restrict__ W,
        const float* __restrict__ bias, const float* __restrict__ res,
        float* __restrict__ C, int M, int N, int K) {
    __shared__ float As[64*68];
    __shared__ float Ws[64*68];
    int tid = threadIdx.x;
    int wid = tid >> 6, lane = tid & 63;
    int wy = wid >> 1, wx = wid & 1;
    int sg = lane >> 3, tg = lane & 7;
    int m0 = blockIdx.y*64, n0 = blockIdx.x*64;
    int r = tid >> 2, c0 = (tid & 3) << 4;
    bool vec = ((K & 3) == 0);
    float acc[4][4];
    #pragma unroll
    for (int i = 0; i < 4; ++i)
        #pragma unroll
        for (int j = 0; j < 4; ++j) acc[i][j] = 0.f;

    for (int k0 = 0; k0 < K; k0 += 64) {
        __syncthreads();
        const float* Ar = A + (size_t)(m0+r)*K + k0;
        const float* Wr = W + (size_t)(n0+r)*K + k0;
        if (vec) {
            #pragma unroll
            for (int i = 0; i < 4; ++i) {
                *(float4*)(&As[r*68 + c0 + 4*i]) = *(const float4*)(Ar + c0 + 4*i);
                *(float4*)(&Ws[r*68 + c0 + 4*i]) = *(const float4*)(Wr + c0 + 4*i);
            }
        } else {
            #pragma unroll
            for (int i = 0; i < 4; ++i)
                #pragma unroll
                for (int e = 0; e < 4; ++e) {
                    int c = c0 + 4*i + e;
                    bool ok = (k0 + c) < K;
                    As[r*68 + c] = ok ? Ar[c] : 0.f;
                    Ws[r*68 + c] = ok ? Wr[c] : 0.f;
                }
        }
        __syncthreads();
        const float* arow = &As[(32*wy + sg)*68];
        const float* brow = &Ws[(32*wx + tg)*68];
        #pragma unroll 2
        for (int d = 0; d < 64; d += 4) {
            float4 b0 = *(const float4*)(brow + 0*544 + d);
            float4 b1 = *(const float4*)(brow + 1*544 + d);
            float4 b2 = *(const float4*)(brow + 2*544 + d);
            float4 b3 = *(const float4*)(brow + 3*544 + d);
            #pragma unroll
            for (int i = 0; i < 4; ++i) {
                float4 a = *(const float4*)(arow + i*544 + d);
                acc[i][0] += a.x*b0.x + a.y*b0.y + a.z*b0.z + a.w*b0.w;
                acc[i][1] += a.x*b1.x + a.y*b1.y + a.z*b1.z + a.w*b1.w;
                acc[i][2] += a.x*b2.x + a.y*b2.y + a.z*b2.z + a.w*b2.w;
                acc[i][3] += a.x*b3.x + a.y*b3.y + a.z*b3.z + a.w*b3.w;
            }
        }
    }
    #pragma unroll
    for (int i = 0; i < 4; ++i) {
        int m = m0 + 32*wy + 8*i + sg;
        #pragma unroll
        for (int j = 0; j < 4; ++j) {
            int n = n0 + 32*wx + 8*j + tg;
            float v = acc[i][j] + bias[n];
            if (res) v += res[(size_t)m*N + n];
            C[(size_t)m*N + n] = v;
        }
    }
}

// ---------------- Plain LayerNorm over D=128 ----------------
__global__ void ln_kernel(const float* __restrict__ X, const float* __restrict__ w,
                          float* __restrict__ Y) {
    int row = blockIdx.x, t = threadIdx.x;  // 128 threads
    float v = X[(size_t)row*128 + t];
    __shared__ float s1[128], s2[128];
    s1[t]=v; s2[t]=v*v; __syncthreads();
    for (int off=64; off>0; off>>=1){
        if (t<off){ s1[t]+=s1[t+off]; s2[t]+=s2[t+off]; }
        __syncthreads();
    }
    float mu = s1[0]*(1.f/128.f);
    float var = s2[0]*(1.f/128.f) - mu*mu;
    Y[(size_t)row*128 + t] = (v-mu)*rsqrtf(var+1e-5f)*w[t];
}

// ---------------- Causal depthwise conv (K=4) + SiLU ----------------
__global__ void conv_silu(const float* __restrict__ X, int ldx,
                          const float* __restrict__ kw, const float* __restrict__ kb,
                          float* __restrict__ Y, int ldy, int C) {
    int idx = blockIdx.x*blockDim.x + threadIdx.x;
    int total = MROWS_*C;
    if (idx >= total) return;
    int c = idx % C; int bs = idx / C;
    int s = bs % S_; int b = bs / S_;
    float acc = kb[c];
    #pragma unroll
    for (int i = 0; i < 4; ++i) {
        int sp = s - 3 + i;
        if (sp >= 0) acc += X[((size_t)b*S_+sp)*ldx + c] * kw[c*4+i];
    }
    Y[((size_t)b*S_+s)*ldy + c] = acc * fsigm(acc);
}

// ---------------- Headwise block-diagonal proj (mLSTM q/k/v, HS=4) ----------------
__global__ void headwise4(const float* __restrict__ X, int ldx,
                          const float* __restrict__ W, const float* __restrict__ bias,
                          float* __restrict__ Y) {
    int idx = blockIdx.x*blockDim.x + threadIdx.x;
    int total = MROWS_*INNER_;
    if (idx >= total) return;
    int co = idx % INNER_; int bs = idx / INNER_;
    int h = co >> 2, o = co & 3;
    const float* Wh = W + ((size_t)h*4 + o)*4;
    const float* xr = X + (size_t)bs*ldx + h*4;
    float acc = bias[co];
    #pragma unroll
    for (int i = 0; i < 4; ++i) acc += xr[i]*Wh[i];
    Y[(size_t)bs*INNER_ + co] = acc;
}

// ---------------- sLSTM all-4-gates headwise (HS=32) ----------------
__global__ void slstm_gates(const float* __restrict__ rc, const float* __restrict__ r,
                            const float* __restrict__ Wi, const float* __restrict__ Wf,
                            const float* __restrict__ Wz, const float* __restrict__ Wo,
                            float* __restrict__ GX) {
    int idx = blockIdx.x*blockDim.x + threadIdx.x;
    int total = MROWS_*128;
    if (idx >= total) return;
    int co = idx % 128; int bs = idx / 128;
    int h = co >> 5, o = co & 31;
    size_t wb = ((size_t)h*32 + o)*32;
    const float* xc_ = rc + (size_t)bs*128 + h*32;
    const float* xr_ = r  + (size_t)bs*128 + h*32;
    float di=0.f, df=0.f, dz=0.f, doo=0.f;
    #pragma unroll
    for (int i = 0; i < 32; ++i) {
        float a = xc_[i], c = xr_[i];
        di  += a*Wi[wb+i];
        df  += a*Wf[wb+i];
        dz  += c*Wz[wb+i];
        doo += c*Wo[wb+i];
    }
    float* g = GX + (size_t)bs*512 + h*128 + o;
    g[0]  = di;
    g[32] = df;
    g[64] = dz;
    g[96] = doo;
}

// ---------------- ig/fg gate projection over concat(q,k,v) ----------------
__global__ void gateproj(const float* __restrict__ q, const float* __restrict__ k,
                         const float* __restrict__ v,
                         const float* __restrict__ Wig, const float* __restrict__ big,
                         const float* __restrict__ Wfg, const float* __restrict__ bfg,
                         float* __restrict__ igp, float* __restrict__ fgp) {
    int bs = blockIdx.x; int lane = threadIdx.x;  // 64 threads
    int b = bs / S_, s = bs % S_;
    const float* qr = q + (size_t)bs*INNER_;
    const float* kr = k + (size_t)bs*INNER_;
    const float* vr = v + (size_t)bs*INNER_;
    float dots[8];
    #pragma unroll
    for (int g=0; g<8; ++g) dots[g]=0.f;
    for (int c = lane; c < INNER_; c += 64) {
        float qv = qr[c], kv = kr[c], vv = vr[c];
        #pragma unroll
        for (int g=0; g<4; ++g) {
            dots[g]   += qv*Wig[g*768+c] + kv*Wig[g*768+256+c] + vv*Wig[g*768+512+c];
            dots[4+g] += qv*Wfg[g*768+c] + kv*Wfg[g*768+256+c] + vv*Wfg[g*768+512+c];
        }
    }
    #pragma unroll
    for (int off=32; off>0; off>>=1)
        #pragma unroll
        for (int g=0; g<8; ++g) dots[g] += __shfl_down(dots[g], off, 64);
    if (lane == 0) {
        #pragma unroll
        for (int g=0; g<4; ++g) {
            igp[((size_t)b*NH_+g)*S_ + s] = dots[g]   + big[g];
            fgp[((size_t)b*NH_+g)*S_ + s] = dots[4+g] + bfg[g];
        }
    }
}

// ---------------- mLSTM decay precompute ----------------
__global__ void mlstm_scan_pre(const float* __restrict__ igp, const float* __restrict__ fgp,
                               float* __restrict__ lc, float* __restrict__ av,
                               float* __restrict__ mx) {
    int bh = blockIdx.x; int t = threadIdx.x;  // 1024 threads
    __shared__ float buf[2][1024];
    float ls = flogsig(fgp[(size_t)bh*S_ + t]);
    int cur = 0;
    buf[0][t] = ls; __syncthreads();
    for (int off=1; off<1024; off<<=1) {
        float x2 = buf[cur][t];
        if (t >= off) x2 += buf[cur][t-off];
        buf[cur^1][t] = x2; cur ^= 1; __syncthreads();
    }
    float lcv = buf[cur][t];
    lc[(size_t)bh*S_+t] = lcv;
    float a = igp[(size_t)bh*S_+t] - lcv;
    av[(size_t)bh*S_+t] = a;
    __syncthreads();
    cur = 0; buf[0][t] = a; __syncthreads();
    for (int off=1; off<1024; off<<=1) {
        float x2 = buf[cur][t];
        if (t >= off) x2 = fmaxf(x2, buf[cur][t-off]);
        buf[cur^1][t] = x2; cur ^= 1; __syncthreads();
    }
    mx[(size_t)bh*S_+t] = buf[cur][t];
}

// ---------------- mLSTM attention: tiled flash-style ----------------
__global__ __launch_bounds__(256, 2) void mlstm_attn_tiled(
        const float* __restrict__ q, const float* __restrict__ k,
        const float* __restrict__ v, const float* __restrict__ lc,
        const float* __restrict__ av, const float* __restrict__ mx,
        float* __restrict__ hc) {
    int bid = blockIdx.x;
    int stile = 15 - (bid & 15);
    int bh = bid >> 4;
    int hh = bh & 3, b = bh >> 2;
    int s0 = stile << 6;
    int tid = threadIdx.x;
    int wid = tid >> 6, lane = tid & 63;
    int wy = wid >> 1, wx = wid & 1;
    int sg = lane >> 3, tg = lane & 7;

    __shared__ float qs[64*68];
    __shared__ float kst[64*68];
    __shared__ float vtT[64*68];
    __shared__ float avt[64], maxsL[64], normL[64], rsumL[128];

    const size_t bhS = (size_t)bh * S_;
    {
        int r = tid >> 2, c0 = (tid & 3) << 4;
        const float* qg = q + ((size_t)(b*S_) + s0 + r)*INNER_ + hh*64;
        #pragma unroll
        for (int i = 0; i < 4; ++i) {
            float4 t4 = *(const float4*)(qg + c0 + 4*i);
            float4 w4; w4.x=t4.x*0.125f; w4.y=t4.y*0.125f; w4.z=t4.z*0.125f; w4.w=t4.w*0.125f;
            *(float4*)(&qs[r*68 + c0 + 4*i]) = w4;
        }
        if (tid < 64) maxsL[tid] = lc[bhS + s0 + tid] + mx[bhS + s0 + tid];
    }
    float msv[4];
    #pragma unroll
    for (int i = 0; i < 4; ++i)
        msv[i] = mx[bhS + s0 + 32*wy + 8*i + sg];

    float O[4][4];
    float rsAcc[4];
    #pragma unroll
    for (int i = 0; i < 4; ++i) {
        rsAcc[i] = 0.f;
        #pragma unroll
        for (int j = 0; j < 4; ++j) O[i][j] = 0.f;
    }

    for (int t0 = 0; t0 <= s0; t0 += 64) {
        __syncthreads();
        {
            int r = tid >> 2, c0 = (tid & 3) << 4;
            const float* kg = k + ((size_t)(b*S_) + t0 + r)*INNER_ + hh*64;
            const float* vg = v + ((size_t)(b*S_) + t0 + r)*INNER_ + hh*64;
            #pragma unroll
            for (int i = 0; i < 4; ++i) {
                *(float4*)(&kst[r*68 + c0 + 4*i]) = *(const float4*)(kg + c0 + 4*i);
                float4 v4 = *(const float4*)(vg + c0 + 4*i);
                int dc = c0 + 4*i;
                vtT[(dc+0)*68 + r] = v4.x;
                vtT[(dc+1)*68 + r] = v4.y;
                vtT[(dc+2)*68 + r] = v4.z;
                vtT[(dc+3)*68 + r] = v4.w;
            }
            if (tid < 64) avt[tid] = av[bhS + t0 + tid];
        }
        __syncthreads();
        float dot[4][4];
        #pragma unroll
        for (int i = 0; i < 4; ++i)
            #pragma unroll
            for (int j = 0; j < 4; ++j) dot[i][j] = 0.f;
        {
            const float* qrow = &qs[(32*wy + sg)*68];
            const float* krow = &kst[(32*wx + tg)*68];
            #pragma unroll 2
            for (int d = 0; d < 64; d += 4) {
                float4 b0 = *(const float4*)(krow + 0*544 + d);
                float4 b1 = *(const float4*)(krow + 1*544 + d);
                float4 b2 = *(const float4*)(krow + 2*544 + d);
                float4 b3 = *(const float4*)(krow + 3*544 + d);
                #pragma unroll
                for (int i = 0; i < 4; ++i) {
                    float4 a = *(const float4*)(qrow + i*544 + d);
                    dot[i][0] += a.x*b0.x + a.y*b0.y + a.z*b0.z + a.w*b0.w;
                    dot[i][1] += a.x*b1.x + a.y*b1.y + a.z*b1.z + a.w*b1.w;
                    dot[i][2] += a.x*b2.x + a.y*b2.y + a.z*b2.z + a.w*b2.w;
                    dot[i][3] += a.x*b3.x + a.y*b3.y + a.z*b3.z + a.w*b3.w;
                }
            }
        }
        __syncthreads();
        #pragma unroll
        for (int i = 0; i < 4; ++i) {
            int s_loc = 32*wy + 8*i + sg;
            float rp = 0.f;
            #pragma unroll
            for (int j = 0; j < 4; ++j) {
                int t_loc = 32*wx + 8*j + tg;
                bool ok = (t0 + t_loc) <= (s0 + s_loc);
                float p = ok ? dot[i][j]*__expf(avt[t_loc] - msv[i]) : 0.f;
                kst[s_loc*68 + t_loc] = p;
                rp += p;
            }
            rp += __shfl_xor(rp, 1);
            rp += __shfl_xor(rp, 2);
            rp += __shfl_xor(rp, 4);
            rsAcc[i] += rp;
        }
        __syncthreads();
        {
            const float* prow = &kst[(32*wy + sg)*68];
            const float* vrow = &vtT[(32*wx + tg)*68];
            #pragma unroll 2
            for (int tt = 0; tt < 64; tt += 4) {
                float4 b0 = *(const float4*)(vrow + 0*544 + tt);
                float4 b1 = *(const float4*)(vrow + 1*544 + tt);
                float4 b2 = *(const float4*)(vrow + 2*544 + tt);
                float4 b3 = *(const float4*)(vrow + 3*544 + tt);
                #pragma unroll
                for (int i = 0; i < 4; ++i) {
                    float4 a = *(const float4*)(prow + i*544 + tt);
                    O[i][0] += a.x*b0.x + a.y*b0.y + a.z*b0.z + a.w*b0.w;
                    O[i][1] += a.x*b1.x + a.y*b1.y + a.z*b1.z + a.w*b1.w;
                    O[i][2] += a.x*b2.x + a.y*b2.y + a.z*b2.z + a.w*b2.w;
                    O[i][3] += a.x*b3.x + a.y*b3.y + a.z*b3.z + a.w*b3.w;
                }
            }
        }
    }
    if (tg == 0) {
        #pragma unroll
        for (int i = 0; i < 4; ++i)
            rsumL[wx*64 + 32*wy + 8*i + sg] = rsAcc[i];
    }
    __syncthreads();
    if (tid < 64) {
        float tot = rsumL[tid] + rsumL[64 + tid];
        normL[tid] = fmaxf(fabsf(tot), __expf(-maxsL[tid])) + 1e-6f;
    }
    __syncthreads();
    #pragma unroll
    for (int i = 0; i < 4; ++i) {
        int s_loc = 32*wy + 8*i + sg;
        float inv = 1.0f / normL[s_loc];
        #pragma unroll
        for (int j = 0; j < 4; ++j) {
            int d_loc = 32*wx + 8*j + tg;
            hc[((size_t)(b*S_) + s0 + s_loc)*INNER_ + hh*64 + d_loc] = O[i][j] * inv;
        }
    }
}

// ---------------- mLSTM output: multihead LN (GS=64) + skip + gate ----------------
__global__ void mlstm_out(const float* __restrict__ hc, const float* __restrict__ xc,
                          const float* __restrict__ up, const float* __restrict__ onw,
                          const float* __restrict__ skip, float* __restrict__ hs) {
    int row = blockIdx.x; int c = threadIdx.x;  // 256 threads
    float v = hc[(size_t)row*INNER_ + c];
    __shared__ float s1[256], s2[256];
    s1[c]=v; s2[c]=v*v; __syncthreads();
    int li = c & 63;
    for (int off=32; off>0; off>>=1){
        if (li < off){ s1[c]+=s1[c+off]; s2[c]+=s2[c+off]; }
        __syncthreads();
    }
    int base = c & ~63;
    float mu = s1[base]*(1.f/64.f);
    float var = s2[base]*(1.f/64.f) - mu*mu;
    float ht = (v-mu)*rsqrtf(var+1e-5f)*onw[c];
    float z = up[(size_t)row*512 + 256 + c];
    hs[(size_t)row*INNER_ + c] = (ht + skip[c]*xc[(size_t)row*INNER_+c]) * (z*fsigm(z));
}

// ---------------- sLSTM scan: ONE WAVE per (b,h), R pinned in regs ----------------
// asm volatile("" : "+v") makes each R value's def opaque: the compiler cannot
// rematerialize/reload it inside the t-loop (round-8 showed VGPR=52 < 64 live
// R floats -> in-loop L1 reloads in the serial chain). 4-way split accumulators
// cut the dependent-FMA chain from 32 to 8 deep.
__global__ __launch_bounds__(64, 1) void slstm_scan_wave(
        const float* __restrict__ gx, const float* __restrict__ R,
        const float* __restrict__ bb, float* __restrict__ ys) {
    int blk = blockIdx.x; int hh = blk & 3; int b = blk >> 2;
    int l = threadIdx.x;  // 0..63
    float Rc0[32], Rc1[32];
    #pragma unroll
    for (int d = 0; d < 32; ++d) {
        Rc0[d] = R[(size_t)(hh*32 + d)*128 + l];
        Rc1[d] = R[(size_t)(hh*32 + d)*128 + l + 64];
        asm volatile("" : "+v"(Rc0[d]));
        asm volatile("" : "+v"(Rc1[d]));
    }
    float bj0 = bb[hh*128 + l], bj1 = bb[hh*128 + l + 64];
    float cst = 0.f, nst = 0.f, mst = 0.f, y = 0.f;
    const float* gbase = gx + (size_t)(b*S_)*512 + hh*128;
    float* ybase = ys + (size_t)(b*S_)*128 + hh*32;
    float ga[4], gb[4];
    #pragma unroll
    for (int u = 0; u < 4; ++u) {
        ga[u] = gbase[(size_t)u*512 + l];
        gb[u] = gbase[(size_t)u*512 + l + 64];
    }
    for (int t = 0; t < S_; t += 4) {
        float gna[4], gnb[4];
        #pragma unroll
        for (int u = 0; u < 4; ++u) {
            int tn = t + 4 + u;
            size_t off = (size_t)(tn < S_ ? tn : 0) * 512;
            gna[u] = gbase[off + l];
            gnb[u] = gbase[off + l + 64];
        }
        #pragma unroll
        for (int u = 0; u < 4; ++u) {
            float a0=0.f, a1=0.f, a2=0.f, a3=0.f;
            float c0=0.f, c1=0.f, c2=0.f, c3=0.f;
            #pragma unroll
            for (int d = 0; d < 32; d += 4) {
                float y0 = __int_as_float(__builtin_amdgcn_readlane(__float_as_int(y), d));
                float y1 = __int_as_float(__builtin_amdgcn_readlane(__float_as_int(y), d+1));
                float y2 = __int_as_float(__builtin_amdgcn_readlane(__float_as_int(y), d+2));
                float y3 = __int_as_float(__builtin_amdgcn_readlane(__float_as_int(y), d+3));
                a0 += y0*Rc0[d];   c0 += y0*Rc1[d];
                a1 += y1*Rc0[d+1]; c1 += y1*Rc1[d+1];
                a2 += y2*Rc0[d+2]; c2 += y2*Rc1[d+2];
                a3 += y3*Rc0[d+3]; c3 += y3*Rc1[d+3];
            }
            float r0 = ga[u] + bj0 + ((a0+a1)+(a2+a3));
            float r1 = gb[u] + bj1 + ((c0+c1)+(c2+c3));
            float fo0 = __shfl_xor(r0, 32, 64);
            float fo1 = __shfl_xor(r1, 32, 64);
            int t_abs = t + u;
            float iraw = r0, zraw = r1, fraw = fo0, oraw = fo1;
            float lfm = mst + flogsig(fraw);
            float mnew = (t_abs == 0) ? iraw : fmaxf(iraw, lfm);
            float og = fsigm(oraw);
            float igv = __expf(iraw - mnew), fgv = __expf(lfm - mnew);
            cst = fgv*cst + igv*ftanh(zraw);
            nst = fgv*nst + igv;
            mst = mnew;
            y = og*cst*frcp(nst);
            if (l < 32) ybase[(size_t)t_abs*128 + l] = y;
        }
        #pragma unroll
        for (int u = 0; u < 4; ++u) { ga[u] = gna[u]; gb[u] = gnb[u]; }
    }
}

// ---------------- sLSTM out: h += mh_ln(ys; GS=32) * gnw ----------------
__global__ void slstm_addnorm(const float* __restrict__ ys, const float* __restrict__ w,
                              float* __restrict__ h) {
    int row = blockIdx.x; int c = threadIdx.x;  // 128
    float v = ys[(size_t)row*128 + c];
    __shared__ float s1[128], s2[128];
    s1[c]=v; s2[c]=v*v; __syncthreads();
    int li = c & 31;
    for (int off=16; off>0; off>>=1){
        if (li < off){ s1[c]+=s1[c+off]; s2[c]+=s2[c+off]; }
        __syncthreads();
    }
    int base = c & ~31;
    float mu = s1[base]*(1.f/32.f);
    float var = s2[base]*(1.f/32.f) - mu*mu;
    h[(size_t)row*128 + c] += (v-mu)*rsqrtf(var+1e-5f)*w[c];
}

// ---------------- FFN activation: gelu(g) * u2 ----------------
__global__ void ffn_act(const float* __restrict__ u, float* __restrict__ act) {
    int idx = blockIdx.x*blockDim.x + threadIdx.x;
    int total = MROWS_*192;
    if (idx >= total) return;
    int j = idx % 192; int m = idx / 192;
    float g  = u[(size_t)m*384 + j];
    float u2 = u[(size_t)m*384 + 192 + j];
    float ge = 0.5f*g*(1.0f + erff(g*0.70710678118f));
    act[(size_t)m*192 + j] = ge*u2;
}

// ---------------- Final FC on last token ----------------
__global__ void final_fc(const float* __restrict__ hp, const float* __restrict__ fcW,
                         const float* __restrict__ fcb, float* __restrict__ out) {
    int b = blockIdx.x; int lane = threadIdx.x;  // 64
    const float* r = hp + ((size_t)b*S_ + (S_-1))*128;
    float acc = r[lane]*fcW[lane] + r[lane+64]*fcW[lane+64];
    #pragma unroll
    for (int off=32; off>0; off>>=1) acc += __shfl_down(acc, off, 64);
    if (lane == 0) out[b] = acc + fcb[0];
}

extern "C" void kernel_launch(void* const* d_in, const int* in_sizes, int n_in,
                              void* d_out, int out_size, void* d_ws, size_t ws_size,
                              hipStream_t stream) {
    const float* x       = (const float*)d_in[0];
    const float* W_in    = (const float*)d_in[1];
    const float* b_in    = (const float*)d_in[2];
    const float* ln0_w   = (const float*)d_in[3];
    const float* m_Wup   = (const float*)d_in[4];
    const float* m_bup   = (const float*)d_in[5];
    const float* m_convk = (const float*)d_in[6];
    const float* m_convb = (const float*)d_in[7];
    const float* m_Wq    = (const float*)d_in[8];
    const float* m_bq    = (const float*)d_in[9];
    const float* m_Wk    = (const float*)d_in[10];
    const float* m_bk    = (const float*)d_in[11];
    const float* m_Wv    = (const float*)d_in[12];
    const float* m_bv    = (const float*)d_in[13];
    const float* m_Wig   = (const float*)d_in[14];
    const float* m_big   = (const float*)d_in[15];
    const float* m_Wfg   = (const float*)d_in[16];
    const float* m_bfg   = (const float*)d_in[17];
    const float* m_onw   = (const float*)d_in[18];
    const float* m_skip  = (const float*)d_in[19];
    const float* m_Wd    = (const float*)d_in[20];
    const float* m_bd    = (const float*)d_in[21];
    const float* ln1_w   = (const float*)d_in[22];
    const float* s_convk = (const float*)d_in[23];
    const float* s_convb = (const float*)d_in[24];
    const float* s_Wi    = (const float*)d_in[25];
    const float* s_Wf    = (const float*)d_in[26];
    const float* s_Wz    = (const float*)d_in[27];
    const float* s_Wo    = (const float*)d_in[28];
    const float* s_R     = (const float*)d_in[29];
    const float* s_b     = (const float*)d_in[30];
    const float* s_gnw   = (const float*)d_in[31];
    const float* ffn_nw  = (const float*)d_in[32];
    const float* f_Wu    = (const float*)d_in[33];
    const float* f_bu    = (const float*)d_in[34];
    const float* f_Wd    = (const float*)d_in[35];
    const float* f_bd    = (const float*)d_in[36];
    const float* post_w  = (const float*)d_in[37];
    const float* fc_W    = (const float*)d_in[38];
    const float* fc_b    = (const float*)d_in[39];
    float* out = (float*)d_out;

    float* W = (float*)d_ws;
    const size_t M1 = 1048576;        // 8192*128
    float* h    = W;                   // 1M
    float* r    = W + 1*M1;            // 1M
    float* up   = W + 2*M1;            // 4M
    float* xc   = W + 6*M1;            // 2M
    float* q    = W + 8*M1;            // 2M
    float* kbuf = W + 10*M1;           // 2M
    float* vbuf = W + 12*M1;           // 2M
    float* hc   = W + 14*M1;           // 2M
    float* igp  = W + 16*M1;
    float* fgp  = igp + 32768;
    float* lc   = fgp + 32768;
    float* av   = lc  + 32768;
    float* mx   = av  + 32768;
    float* hs   = q;
    float* gx   = kbuf;
    float* ys   = hc;
    float* rc   = xc;
    float* u    = up;
    float* act  = q;
    float* hp   = r;

    // 1. h = x @ W_in^T + b_in
    gemm_bias_big<<<dim3(128/64, MROWS_/64), 256, 0, stream>>>(x, W_in, b_in, nullptr, h, MROWS_, 128, F_);
    // 2. r = LN(h)*ln0_w
    ln_kernel<<<MROWS_, 128, 0, stream>>>(h, ln0_w, r);
    // 3. up = r @ m_Wup^T + m_bup
    gemm_bias_big<<<dim3(512/64, MROWS_/64), 256, 0, stream>>>(r, m_Wup, m_bup, nullptr, up, MROWS_, 512, 128);
    // 4. xc = silu(causal_conv(xm))
    conv_silu<<<(MROWS_*256)/256, 256, 0, stream>>>(up, 512, m_convk, m_convb, xc, 256, 256);
    // 5. q,k,v headwise
    headwise4<<<(MROWS_*256)/256, 256, 0, stream>>>(xc, 256, m_Wq, m_bq, q);
    headwise4<<<(MROWS_*256)/256, 256, 0, stream>>>(xc, 256, m_Wk, m_bk, kbuf);
    headwise4<<<(MROWS_*256)/256, 256, 0, stream>>>(up, 512, m_Wv, m_bv, vbuf);
    // 6. ig/fg projections
    gateproj<<<MROWS_, 64, 0, stream>>>(q, kbuf, vbuf, m_Wig, m_big, m_Wfg, m_bfg, igp, fgp);
    // 7. decay precompute
    mlstm_scan_pre<<<B_*NH_, 1024, 0, stream>>>(igp, fgp, lc, av, mx);
    // 8. attention (tiled)
    mlstm_attn_tiled<<<B_*NH_*16, 256, 0, stream>>>(q, kbuf, vbuf, lc, av, mx, hc);
    // 9. multihead LN + skip + gate
    mlstm_out<<<MROWS_, 256, 0, stream>>>(hc, xc, up, m_onw, m_skip, hs);
    // 10. h += hs @ m_Wd^T + m_bd
    gemm_bias_big<<<dim3(128/64, MROWS_/64), 256, 0, stream>>>(hs, m_Wd, m_bd, h, h, MROWS_, 128, 256);
    // 11. r = LN(h)*ln1_w
    ln_kernel<<<MROWS_, 128, 0, stream>>>(h, ln1_w, r);
    // 12. rc = silu(causal_conv(r))
    conv_silu<<<(MROWS_*128)/256, 256, 0, stream>>>(r, 128, s_convk, s_convb, rc, 128, 128);
    // 13. sLSTM gates (all 4 in one launch)
    slstm_gates<<<(MROWS_*128)/256, 256, 0, stream>>>(rc, r, s_Wi, s_Wf, s_Wz, s_Wo, gx);
    // 14. sequential scan (single wave per (b,h), R pinned via asm)
    slstm_scan_wave<<<B_*NH_, 64, 0, stream>>>(gx, s_R, s_b, ys);
    // 15. h += mh_ln(ys)*s_gnw
    slstm_addnorm<<<MROWS_, 128, 0, stream>>>(ys, s_gnw, h);
    // 16. r = LN(h)*ffn_nw
    ln_kernel<<<MROWS_, 128, 0, stream>>>(h, ffn_nw, r);
    // 17. u = r @ f_Wu^T + f_bu
    gemm_bias_big<<<dim3(384/64, MROWS_/64), 256, 0, stream>>>(r, f_Wu, f_bu, nullptr, u, MROWS_, 384, 128);
    // 18. act = gelu(g)*u2
    ffn_act<<<(MROWS_*192)/256, 256, 0, stream>>>(u, act);
    // 19. h += act @ f_Wd^T + f_bd
    gemm_bias_big<<<dim3(128/64, MROWS_/64), 256, 0, stream>>>(act, f_Wd, f_bd, h, h, MROWS_, 128, 192);
    // 20. hp = LN(h)*post_w
    ln_kernel<<<MROWS_, 128, 0, stream>>>(h, post_w, hp);
    // 21. out = hp[:, -1, :] @ fc_W^T + fc_b
    final_fc<<<B_, 64, 0, stream>>>(hp, fc_W, fc_b, out);
    (void)in_sizes; (void)n_in; (void)out_size; (void)ws_size;
}

// Round 10
// 957.530 us; speedup vs baseline: 1.3150x; 1.0290x over previous
//
#include <hip/hip_runtime.h>
#include <hip/hip_bf16.h>
#include <math.h>

#define B_ 8
#define S_ 1024
#define F_ 75
#define D_ 128
#define INNER_ 256
#define NH_ 4
#define DH_ 64
#define MROWS_ (B_*S_)   // 8192

static __device__ __forceinline__ float frcp(float x){ return __builtin_amdgcn_rcpf(x); }
static __device__ __forceinline__ float fsigm(float x){ return frcp(1.0f + __expf(-x)); }
static __device__ __forceinline__ float flogsig(float x){
    return fminf(x, 0.f) - __logf(1.0f + __expf(-fabsf(x)));
}
static __device__ __forceinline__ float ftanh(float z){
    return 1.0f - 2.0f*frcp(__expf(2.0f*z) + 1.0f);
}

// ---------------- Tiled GEMM: C = A @ W^T + bias (+ res) ----------------
__global__ __launch_bounds__(256, 2) void gemm_bias_big(
        const float* __restrict__ A, const float* __restrict__ W,
        const float* __restrict__ bias, const float* __restrict__ res,
        float* __restrict__ C, int M, int N, int K) {
    __shared__ float As[64*68];
    __shared__ float Ws[64*68];
    int tid = threadIdx.x;
    int wid = tid >> 6, lane = tid & 63;
    int wy = wid >> 1, wx = wid & 1;
    int sg = lane >> 3, tg = lane & 7;
    int m0 = blockIdx.y*64, n0 = blockIdx.x*64;
    int r = tid >> 2, c0 = (tid & 3) << 4;
    bool vec = ((K & 3) == 0);
    float acc[4][4];
    #pragma unroll
    for (int i = 0; i < 4; ++i)
        #pragma unroll
        for (int j = 0; j < 4; ++j) acc[i][j] = 0.f;

    for (int k0 = 0; k0 < K; k0 += 64) {
        __syncthreads();
        const float* Ar = A + (size_t)(m0+r)*K + k0;
        const float* Wr = W + (size_t)(n0+r)*K + k0;
        if (vec) {
            #pragma unroll
            for (int i = 0; i < 4; ++i) {
                *(float4*)(&As[r*68 + c0 + 4*i]) = *(const float4*)(Ar + c0 + 4*i);
                *(float4*)(&Ws[r*68 + c0 + 4*i]) = *(const float4*)(Wr + c0 + 4*i);
            }
        } else {
            #pragma unroll
            for (int i = 0; i < 4; ++i)
                #pragma unroll
                for (int e = 0; e < 4; ++e) {
                    int c = c0 + 4*i + e;
                    bool ok = (k0 + c) < K;
                    As[r*68 + c] = ok ? Ar[c] : 0.f;
                    Ws[r*68 + c] = ok ? Wr[c] : 0.f;
                }
        }
        __syncthreads();
        const float* arow = &As[(32*wy + sg)*68];
        const float* brow = &Ws[(32*wx + tg)*68];
        #pragma unroll 2
        for (int d = 0; d < 64; d += 4) {
            float4 b0 = *(const float4*)(brow + 0*544 + d);
            float4 b1 = *(const float4*)(brow + 1*544 + d);
            float4 b2 = *(const float4*)(brow + 2*544 + d);
            float4 b3 = *(const float4*)(brow + 3*544 + d);
            #pragma unroll
            for (int i = 0; i < 4; ++i) {
                float4 a = *(const float4*)(arow + i*544 + d);
                acc[i][0] += a.x*b0.x + a.y*b0.y + a.z*b0.z + a.w*b0.w;
                acc[i][1] += a.x*b1.x + a.y*b1.y + a.z*b1.z + a.w*b1.w;
                acc[i][2] += a.x*b2.x + a.y*b2.y + a.z*b2.z + a.w*b2.w;
                acc[i][3] += a.x*b3.x + a.y*b3.y + a.z*b3.z + a.w*b3.w;
            }
        }
    }
    #pragma unroll
    for (int i = 0; i < 4; ++i) {
        int m = m0 + 32*wy + 8*i + sg;
        #pragma unroll
        for (int j = 0; j < 4; ++j) {
            int n = n0 + 32*wx + 8*j + tg;
            float v = acc[i][j] + bias[n];
            if (res) v += res[(size_t)m*N + n];
            C[(size_t)m*N + n] = v;
        }
    }
}

// ---------------- Plain LayerNorm over D=128 ----------------
__global__ void ln_kernel(const float* __restrict__ X, const float* __restrict__ w,
                          float* __restrict__ Y) {
    int row = blockIdx.x, t = threadIdx.x;  // 128 threads
    float v = X[(size_t)row*128 + t];
    __shared__ float s1[128], s2[128];
    s1[t]=v; s2[t]=v*v; __syncthreads();
    for (int off=64; off>0; off>>=1){
        if (t<off){ s1[t]+=s1[t+off]; s2[t]+=s2[t+off]; }
        __syncthreads();
    }
    float mu = s1[0]*(1.f/128.f);
    float var = s2[0]*(1.f/128.f) - mu*mu;
    Y[(size_t)row*128 + t] = (v-mu)*rsqrtf(var+1e-5f)*w[t];
}

// ---------------- Causal depthwise conv (K=4) + SiLU ----------------
__global__ void conv_silu(const float* __restrict__ X, int ldx,
                          const float* __restrict__ kw, const float* __restrict__ kb,
                          float* __restrict__ Y, int ldy, int C) {
    int idx = blockIdx.x*blockDim.x + threadIdx.x;
    int total = MROWS_*C;
    if (idx >= total) return;
    int c = idx % C; int bs = idx / C;
    int s = bs % S_; int b = bs / S_;
    float acc = kb[c];
    #pragma unroll
    for (int i = 0; i < 4; ++i) {
        int sp = s - 3 + i;
        if (sp >= 0) acc += X[((size_t)b*S_+sp)*ldx + c] * kw[c*4+i];
    }
    Y[((size_t)b*S_+s)*ldy + c] = acc * fsigm(acc);
}

// ---------------- Headwise block-diagonal proj (mLSTM q/k/v, HS=4) ----------------
__global__ void headwise4(const float* __restrict__ X, int ldx,
                          const float* __restrict__ W, const float* __restrict__ bias,
                          float* __restrict__ Y) {
    int idx = blockIdx.x*blockDim.x + threadIdx.x;
    int total = MROWS_*INNER_;
    if (idx >= total) return;
    int co = idx % INNER_; int bs = idx / INNER_;
    int h = co >> 2, o = co & 3;
    const float* Wh = W + ((size_t)h*4 + o)*4;
    const float* xr = X + (size_t)bs*ldx + h*4;
    float acc = bias[co];
    #pragma unroll
    for (int i = 0; i < 4; ++i) acc += xr[i]*Wh[i];
    Y[(size_t)bs*INNER_ + co] = acc;
}

// ---------------- sLSTM all-4-gates headwise (HS=32) ----------------
__global__ void slstm_gates(const float* __restrict__ rc, const float* __restrict__ r,
                            const float* __restrict__ Wi, const float* __restrict__ Wf,
                            const float* __restrict__ Wz, const float* __restrict__ Wo,
                            float* __restrict__ GX) {
    int idx = blockIdx.x*blockDim.x + threadIdx.x;
    int total = MROWS_*128;
    if (idx >= total) return;
    int co = idx % 128; int bs = idx / 128;
    int h = co >> 5, o = co & 31;
    size_t wb = ((size_t)h*32 + o)*32;
    const float* xc_ = rc + (size_t)bs*128 + h*32;
    const float* xr_ = r  + (size_t)bs*128 + h*32;
    float di=0.f, df=0.f, dz=0.f, doo=0.f;
    #pragma unroll
    for (int i = 0; i < 32; ++i) {
        float a = xc_[i], c = xr_[i];
        di  += a*Wi[wb+i];
        df  += a*Wf[wb+i];
        dz  += c*Wz[wb+i];
        doo += c*Wo[wb+i];
    }
    float* g = GX + (size_t)bs*512 + h*128 + o;
    g[0]  = di;
    g[32] = df;
    g[64] = dz;
    g[96] = doo;
}

// ---------------- ig/fg gate projection over concat(q,k,v) ----------------
__global__ void gateproj(const float* __restrict__ q, const float* __restrict__ k,
                         const float* __restrict__ v,
                         const float* __restrict__ Wig, const float* __restrict__ big,
                         const float* __restrict__ Wfg, const float* __restrict__ bfg,
                         float* __restrict__ igp, float* __restrict__ fgp) {
    int bs = blockIdx.x; int lane = threadIdx.x;  // 64 threads
    int b = bs / S_, s = bs % S_;
    const float* qr = q + (size_t)bs*INNER_;
    const float* kr = k + (size_t)bs*INNER_;
    const float* vr = v + (size_t)bs*INNER_;
    float dots[8];
    #pragma unroll
    for (int g=0; g<8; ++g) dots[g]=0.f;
    for (int c = lane; c < INNER_; c += 64) {
        float qv = qr[c], kv = kr[c], vv = vr[c];
        #pragma unroll
        for (int g=0; g<4; ++g) {
            dots[g]   += qv*Wig[g*768+c] + kv*Wig[g*768+256+c] + vv*Wig[g*768+512+c];
            dots[4+g] += qv*Wfg[g*768+c] + kv*Wfg[g*768+256+c] + vv*Wfg[g*768+512+c];
        }
    }
    #pragma unroll
    for (int off=32; off>0; off>>=1)
        #pragma unroll
        for (int g=0; g<8; ++g) dots[g] += __shfl_down(dots[g], off, 64);
    if (lane == 0) {
        #pragma unroll
        for (int g=0; g<4; ++g) {
            igp[((size_t)b*NH_+g)*S_ + s] = dots[g]   + big[g];
            fgp[((size_t)b*NH_+g)*S_ + s] = dots[4+g] + bfg[g];
        }
    }
}

// ---------------- mLSTM decay precompute ----------------
__global__ void mlstm_scan_pre(const float* __restrict__ igp, const float* __restrict__ fgp,
                               float* __restrict__ lc, float* __restrict__ av,
                               float* __restrict__ mx) {
    int bh = blockIdx.x; int t = threadIdx.x;  // 1024 threads
    __shared__ float buf[2][1024];
    float ls = flogsig(fgp[(size_t)bh*S_ + t]);
    int cur = 0;
    buf[0][t] = ls; __syncthreads();
    for (int off=1; off<1024; off<<=1) {
        float x2 = buf[cur][t];
        if (t >= off) x2 += buf[cur][t-off];
        buf[cur^1][t] = x2; cur ^= 1; __syncthreads();
    }
    float lcv = buf[cur][t];
    lc[(size_t)bh*S_+t] = lcv;
    float a = igp[(size_t)bh*S_+t] - lcv;
    av[(size_t)bh*S_+t] = a;
    __syncthreads();
    cur = 0; buf[0][t] = a; __syncthreads();
    for (int off=1; off<1024; off<<=1) {
        float x2 = buf[cur][t];
        if (t >= off) x2 = fmaxf(x2, buf[cur][t-off]);
        buf[cur^1][t] = x2; cur ^= 1; __syncthreads();
    }
    mx[(size_t)bh*S_+t] = buf[cur][t];
}

// ---------------- mLSTM attention: tiled flash-style ----------------
__global__ __launch_bounds__(256, 2) void mlstm_attn_tiled(
        const float* __restrict__ q, const float* __restrict__ k,
        const float* __restrict__ v, const float* __restrict__ lc,
        const float* __restrict__ av, const float* __restrict__ mx,
        float* __restrict__ hc) {
    int bid = blockIdx.x;
    int stile = 15 - (bid & 15);
    int bh = bid >> 4;
    int hh = bh & 3, b = bh >> 2;
    int s0 = stile << 6;
    int tid = threadIdx.x;
    int wid = tid >> 6, lane = tid & 63;
    int wy = wid >> 1, wx = wid & 1;
    int sg = lane >> 3, tg = lane & 7;

    __shared__ float qs[64*68];
    __shared__ float kst[64*68];
    __shared__ float vtT[64*68];
    __shared__ float avt[64], maxsL[64], normL[64], rsumL[128];

    const size_t bhS = (size_t)bh * S_;
    {
        int r = tid >> 2, c0 = (tid & 3) << 4;
        const float* qg = q + ((size_t)(b*S_) + s0 + r)*INNER_ + hh*64;
        #pragma unroll
        for (int i = 0; i < 4; ++i) {
            float4 t4 = *(const float4*)(qg + c0 + 4*i);
            float4 w4; w4.x=t4.x*0.125f; w4.y=t4.y*0.125f; w4.z=t4.z*0.125f; w4.w=t4.w*0.125f;
            *(float4*)(&qs[r*68 + c0 + 4*i]) = w4;
        }
        if (tid < 64) maxsL[tid] = lc[bhS + s0 + tid] + mx[bhS + s0 + tid];
    }
    float msv[4];
    #pragma unroll
    for (int i = 0; i < 4; ++i)
        msv[i] = mx[bhS + s0 + 32*wy + 8*i + sg];

    float O[4][4];
    float rsAcc[4];
    #pragma unroll
    for (int i = 0; i < 4; ++i) {
        rsAcc[i] = 0.f;
        #pragma unroll
        for (int j = 0; j < 4; ++j) O[i][j] = 0.f;
    }

    for (int t0 = 0; t0 <= s0; t0 += 64) {
        __syncthreads();
        {
            int r = tid >> 2, c0 = (tid & 3) << 4;
            const float* kg = k + ((size_t)(b*S_) + t0 + r)*INNER_ + hh*64;
            const float* vg = v + ((size_t)(b*S_) + t0 + r)*INNER_ + hh*64;
            #pragma unroll
            for (int i = 0; i < 4; ++i) {
                *(float4*)(&kst[r*68 + c0 + 4*i]) = *(const float4*)(kg + c0 + 4*i);
                float4 v4 = *(const float4*)(vg + c0 + 4*i);
                int dc = c0 + 4*i;
                vtT[(dc+0)*68 + r] = v4.x;
                vtT[(dc+1)*68 + r] = v4.y;
                vtT[(dc+2)*68 + r] = v4.z;
                vtT[(dc+3)*68 + r] = v4.w;
            }
            if (tid < 64) avt[tid] = av[bhS + t0 + tid];
        }
        __syncthreads();
        float dot[4][4];
        #pragma unroll
        for (int i = 0; i < 4; ++i)
            #pragma unroll
            for (int j = 0; j < 4; ++j) dot[i][j] = 0.f;
        {
            const float* qrow = &qs[(32*wy + sg)*68];
            const float* krow = &kst[(32*wx + tg)*68];
            #pragma unroll 2
            for (int d = 0; d < 64; d += 4) {
                float4 b0 = *(const float4*)(krow + 0*544 + d);
                float4 b1 = *(const float4*)(krow + 1*544 + d);
                float4 b2 = *(const float4*)(krow + 2*544 + d);
                float4 b3 = *(const float4*)(krow + 3*544 + d);
                #pragma unroll
                for (int i = 0; i < 4; ++i) {
                    float4 a = *(const float4*)(qrow + i*544 + d);
                    dot[i][0] += a.x*b0.x + a.y*b0.y + a.z*b0.z + a.w*b0.w;
                    dot[i][1] += a.x*b1.x + a.y*b1.y + a.z*b1.z + a.w*b1.w;
                    dot[i][2] += a.x*b2.x + a.y*b2.y + a.z*b2.z + a.w*b2.w;
                    dot[i][3] += a.x*b3.x + a.y*b3.y + a.z*b3.z + a.w*b3.w;
                }
            }
        }
        __syncthreads();
        #pragma unroll
        for (int i = 0; i < 4; ++i) {
            int s_loc = 32*wy + 8*i + sg;
            float rp = 0.f;
            #pragma unroll
            for (int j = 0; j < 4; ++j) {
                int t_loc = 32*wx + 8*j + tg;
                bool ok = (t0 + t_loc) <= (s0 + s_loc);
                float p = ok ? dot[i][j]*__expf(avt[t_loc] - msv[i]) : 0.f;
                kst[s_loc*68 + t_loc] = p;
                rp += p;
            }
            rp += __shfl_xor(rp, 1);
            rp += __shfl_xor(rp, 2);
            rp += __shfl_xor(rp, 4);
            rsAcc[i] += rp;
        }
        __syncthreads();
        {
            const float* prow = &kst[(32*wy + sg)*68];
            const float* vrow = &vtT[(32*wx + tg)*68];
            #pragma unroll 2
            for (int tt = 0; tt < 64; tt += 4) {
                float4 b0 = *(const float4*)(vrow + 0*544 + tt);
                float4 b1 = *(const float4*)(vrow + 1*544 + tt);
                float4 b2 = *(const float4*)(vrow + 2*544 + tt);
                float4 b3 = *(const float4*)(vrow + 3*544 + tt);
                #pragma unroll
                for (int i = 0; i < 4; ++i) {
                    float4 a = *(const float4*)(prow + i*544 + tt);
                    O[i][0] += a.x*b0.x + a.y*b0.y + a.z*b0.z + a.w*b0.w;
                    O[i][1] += a.x*b1.x + a.y*b1.y + a.z*b1.z + a.w*b1.w;
                    O[i][2] += a.x*b2.x + a.y*b2.y + a.z*b2.z + a.w*b2.w;
                    O[i][3] += a.x*b3.x + a.y*b3.y + a.z*b3.z + a.w*b3.w;
                }
            }
        }
    }
    if (tg == 0) {
        #pragma unroll
        for (int i = 0; i < 4; ++i)
            rsumL[wx*64 + 32*wy + 8*i + sg] = rsAcc[i];
    }
    __syncthreads();
    if (tid < 64) {
        float tot = rsumL[tid] + rsumL[64 + tid];
        normL[tid] = fmaxf(fabsf(tot), __expf(-maxsL[tid])) + 1e-6f;
    }
    __syncthreads();
    #pragma unroll
    for (int i = 0; i < 4; ++i) {
        int s_loc = 32*wy + 8*i + sg;
        float inv = 1.0f / normL[s_loc];
        #pragma unroll
        for (int j = 0; j < 4; ++j) {
            int d_loc = 32*wx + 8*j + tg;
            hc[((size_t)(b*S_) + s0 + s_loc)*INNER_ + hh*64 + d_loc] = O[i][j] * inv;
        }
    }
}

// ---------------- mLSTM output: multihead LN (GS=64) + skip + gate ----------------
__global__ void mlstm_out(const float* __restrict__ hc, const float* __restrict__ xc,
                          const float* __restrict__ up, const float* __restrict__ onw,
                          const float* __restrict__ skip, float* __restrict__ hs) {
    int row = blockIdx.x; int c = threadIdx.x;  // 256 threads
    float v = hc[(size_t)row*INNER_ + c];
    __shared__ float s1[256], s2[256];
    s1[c]=v; s2[c]=v*v; __syncthreads();
    int li = c & 63;
    for (int off=32; off>0; off>>=1){
        if (li < off){ s1[c]+=s1[c+off]; s2[c]+=s2[c+off]; }
        __syncthreads();
    }
    int base = c & ~63;
    float mu = s1[base]*(1.f/64.f);
    float var = s2[base]*(1.f/64.f) - mu*mu;
    float ht = (v-mu)*rsqrtf(var+1e-5f)*onw[c];
    float z = up[(size_t)row*512 + 256 + c];
    hs[(size_t)row*INNER_ + c] = (ht + skip[c]*xc[(size_t)row*INNER_+c]) * (z*fsigm(z));
}

// ---------------- sLSTM scan: pair-lane layout, DPP gate exchange ----------------
// Lane l: element e = l>>1, gate-pair p = l&1 (p=0 -> i,z ; p=1 -> f,o).
// The i/f and z/o exchange is quad_perm [1,0,3,2] (mov_dpp 0xB1) — VALU-pipe,
// ~8 cyc, replacing two ~120-cyc DS shfl_xor(32) in the serial chain.
// y[e] is computed redundantly on both lanes of a pair; readlane(y, 2d)
// broadcasts for the matvec. R pinned in regs via opaque asm.
__global__ __launch_bounds__(64, 1) void slstm_scan_wave(
        const float* __restrict__ gx, const float* __restrict__ R,
        const float* __restrict__ bb, float* __restrict__ ys) {
    int blk = blockIdx.x; int hh = blk & 3; int b = blk >> 2;
    int l = threadIdx.x;  // 0..63
    int e = l >> 1, p = l & 1;
    int o0 = p*32 + e, o1 = (p+2)*32 + e;
    float Rc0[32], Rc1[32];
    #pragma unroll
    for (int d = 0; d < 32; ++d) {
        Rc0[d] = R[(size_t)(hh*32 + d)*128 + o0];
        Rc1[d] = R[(size_t)(hh*32 + d)*128 + o1];
        asm volatile("" : "+v"(Rc0[d]));
        asm volatile("" : "+v"(Rc1[d]));
    }
    float bj0 = bb[hh*128 + o0], bj1 = bb[hh*128 + o1];
    float cst = 0.f, nst = 0.f, mst = 0.f, y = 0.f;
    const float* gbase = gx + (size_t)(b*S_)*512 + hh*128;
    float* ybase = ys + (size_t)(b*S_)*128 + hh*32 + e;
    float ga[4], gb[4];
    #pragma unroll
    for (int u = 0; u < 4; ++u) {
        ga[u] = gbase[(size_t)u*512 + o0];
        gb[u] = gbase[(size_t)u*512 + o1];
    }
    for (int t = 0; t < S_; t += 4) {
        float gna[4], gnb[4];
        #pragma unroll
        for (int u = 0; u < 4; ++u) {
            int tn = t + 4 + u;
            size_t off = (size_t)(tn < S_ ? tn : 0) * 512;
            gna[u] = gbase[off + o0];
            gnb[u] = gbase[off + o1];
        }
        #pragma unroll
        for (int u = 0; u < 4; ++u) {
            float a0=0.f, a1=0.f, a2=0.f, a3=0.f;
            float c0=0.f, c1=0.f, c2=0.f, c3=0.f;
            #pragma unroll
            for (int d = 0; d < 32; d += 4) {
                float y0 = __int_as_float(__builtin_amdgcn_readlane(__float_as_int(y), 2*d));
                float y1 = __int_as_float(__builtin_amdgcn_readlane(__float_as_int(y), 2*d+2));
                float y2 = __int_as_float(__builtin_amdgcn_readlane(__float_as_int(y), 2*d+4));
                float y3 = __int_as_float(__builtin_amdgcn_readlane(__float_as_int(y), 2*d+6));
                a0 += y0*Rc0[d];   c0 += y0*Rc1[d];
                a1 += y1*Rc0[d+1]; c1 += y1*Rc1[d+1];
                a2 += y2*Rc0[d+2]; c2 += y2*Rc1[d+2];
                a3 += y3*Rc0[d+3]; c3 += y3*Rc1[d+3];
            }
            float r0 = ga[u] + bj0 + ((a0+a1)+(a2+a3));
            float r1 = gb[u] + bj1 + ((c0+c1)+(c2+c3));
            // quad_perm [1,0,3,2] = xor-1 exchange within lane pairs
            float fo0 = __int_as_float(__builtin_amdgcn_mov_dpp(__float_as_int(r0), 0xB1, 0xF, 0xF, true));
            float fo1 = __int_as_float(__builtin_amdgcn_mov_dpp(__float_as_int(r1), 0xB1, 0xF, 0xF, true));
            float iraw = p ? fo0 : r0;
            float fraw = p ? r0 : fo0;
            float zraw = p ? fo1 : r1;
            float oraw = p ? r1 : fo1;
            int t_abs = t + u;
            float lfm = mst + flogsig(fraw);
            float mnew = (t_abs == 0) ? iraw : fmaxf(iraw, lfm);
            float igv = __expf(iraw - mnew), fgv = __expf(lfm - mnew);
            cst = fgv*cst + igv*ftanh(zraw);
            nst = fgv*nst + igv;
            mst = mnew;
            // y = sigm(oraw)*cst/nst = cst * rcp(nst*(1+exp(-oraw)))  (one rcp)
            y = cst * frcp(nst * (1.0f + __expf(-oraw)));
            if (p == 0) ybase[(size_t)t_abs*128] = y;
        }
        #pragma unroll
        for (int u = 0; u < 4; ++u) { ga[u] = gna[u]; gb[u] = gnb[u]; }
    }
}

// ---------------- sLSTM out: h += mh_ln(ys; GS=32) * gnw ----------------
__global__ void slstm_addnorm(const float* __restrict__ ys, const float* __restrict__ w,
                              float* __restrict__ h) {
    int row = blockIdx.x; int c = threadIdx.x;  // 128
    float v = ys[(size_t)row*128 + c];
    __shared__ float s1[128], s2[128];
    s1[c]=v; s2[c]=v*v; __syncthreads();
    int li = c & 31;
    for (int off=16; off>0; off>>=1){
        if (li < off){ s1[c]+=s1[c+off]; s2[c]+=s2[c+off]; }
        __syncthreads();
    }
    int base = c & ~31;
    float mu = s1[base]*(1.f/32.f);
    float var = s2[base]*(1.f/32.f) - mu*mu;
    h[(size_t)row*128 + c] += (v-mu)*rsqrtf(var+1e-5f)*w[c];
}

// ---------------- FFN activation: gelu(g) * u2 ----------------
__global__ void ffn_act(const float* __restrict__ u, float* __restrict__ act) {
    int idx = blockIdx.x*blockDim.x + threadIdx.x;
    int total = MROWS_*192;
    if (idx >= total) return;
    int j = idx % 192; int m = idx / 192;
    float g  = u[(size_t)m*384 + j];
    float u2 = u[(size_t)m*384 + 192 + j];
    float ge = 0.5f*g*(1.0f + erff(g*0.70710678118f));
    act[(size_t)m*192 + j] = ge*u2;
}

// ---------------- Final FC on last token ----------------
__global__ void final_fc(const float* __restrict__ hp, const float* __restrict__ fcW,
                         const float* __restrict__ fcb, float* __restrict__ out) {
    int b = blockIdx.x; int lane = threadIdx.x;  // 64
    const float* r = hp + ((size_t)b*S_ + (S_-1))*128;
    float acc = r[lane]*fcW[lane] + r[lane+64]*fcW[lane+64];
    #pragma unroll
    for (int off=32; off>0; off>>=1) acc += __shfl_down(acc, off, 64);
    if (lane == 0) out[b] = acc + fcb[0];
}

extern "C" void kernel_launch(void* const* d_in, const int* in_sizes, int n_in,
                              void* d_out, int out_size, void* d_ws, size_t ws_size,
                              hipStream_t stream) {
    const float* x       = (const float*)d_in[0];
    const float* W_in    = (const float*)d_in[1];
    const float* b_in    = (const float*)d_in[2];
    const float* ln0_w   = (const float*)d_in[3];
    const float* m_Wup   = (const float*)d_in[4];
    const float* m_bup   = (const float*)d_in[5];
    const float* m_convk = (const float*)d_in[6];
    const float* m_convb = (const float*)d_in[7];
    const float* m_Wq    = (const float*)d_in[8];
    const float* m_bq    = (const float*)d_in[9];
    const float* m_Wk    = (const float*)d_in[10];
    const float* m_bk    = (const float*)d_in[11];
    const float* m_Wv    = (const float*)d_in[12];
    const float* m_bv    = (const float*)d_in[13];
    const float* m_Wig   = (const float*)d_in[14];
    const float* m_big   = (const float*)d_in[15];
    const float* m_Wfg   = (const float*)d_in[16];
    const float* m_bfg   = (const float*)d_in[17];
    const float* m_onw   = (const float*)d_in[18];
    const float* m_skip  = (const float*)d_in[19];
    const float* m_Wd    = (const float*)d_in[20];
    const float* m_bd    = (const float*)d_in[21];
    const float* ln1_w   = (const float*)d_in[22];
    const float* s_convk = (const float*)d_in[23];
    const float* s_convb = (const float*)d_in[24];
    const float* s_Wi    = (const float*)d_in[25];
    const float* s_Wf    = (const float*)d_in[26];
    const float* s_Wz    = (const float*)d_in[27];
    const float* s_Wo    = (const float*)d_in[28];
    const float* s_R     = (const float*)d_in[29];
    const float* s_b     = (const float*)d_in[30];
    const float* s_gnw   = (const float*)d_in[31];
    const float* ffn_nw  = (const float*)d_in[32];
    const float* f_Wu    = (const float*)d_in[33];
    const float* f_bu    = (const float*)d_in[34];
    const float* f_Wd    = (const float*)d_in[35];
    const float* f_bd    = (const float*)d_in[36];
    const float* post_w  = (const float*)d_in[37];
    const float* fc_W    = (const float*)d_in[38];
    const float* fc_b    = (const float*)d_in[39];
    float* out = (float*)d_out;

    float* W = (float*)d_ws;
    const size_t M1 = 1048576;        // 8192*128
    float* h    = W;                   // 1M
    float* r    = W + 1*M1;            // 1M
    float* up   = W + 2*M1;            // 4M
    float* xc   = W + 6*M1;            // 2M
    float* q    = W + 8*M1;            // 2M
    float* kbuf = W + 10*M1;           // 2M
    float* vbuf = W + 12*M1;           // 2M
    float* hc   = W + 14*M1;           // 2M
    float* igp  = W + 16*M1;
    float* fgp  = igp + 32768;
    float* lc   = fgp + 32768;
    float* av   = lc  + 32768;
    float* mx   = av  + 32768;
    float* hs   = q;
    float* gx   = kbuf;
    float* ys   = hc;
    float* rc   = xc;
    float* u    = up;
    float* act  = q;
    float* hp   = r;

    // 1. h = x @ W_in^T + b_in
    gemm_bias_big<<<dim3(128/64, MROWS_/64), 256, 0, stream>>>(x, W_in, b_in, nullptr, h, MROWS_, 128, F_);
    // 2. r = LN(h)*ln0_w
    ln_kernel<<<MROWS_, 128, 0, stream>>>(h, ln0_w, r);
    // 3. up = r @ m_Wup^T + m_bup
    gemm_bias_big<<<dim3(512/64, MROWS_/64), 256, 0, stream>>>(r, m_Wup, m_bup, nullptr, up, MROWS_, 512, 128);
    // 4. xc = silu(causal_conv(xm))
    conv_silu<<<(MROWS_*256)/256, 256, 0, stream>>>(up, 512, m_convk, m_convb, xc, 256, 256);
    // 5. q,k,v headwise
    headwise4<<<(MROWS_*256)/256, 256, 0, stream>>>(xc, 256, m_Wq, m_bq, q);
    headwise4<<<(MROWS_*256)/256, 256, 0, stream>>>(xc, 256, m_Wk, m_bk, kbuf);
    headwise4<<<(MROWS_*256)/256, 256, 0, stream>>>(up, 512, m_Wv, m_bv, vbuf);
    // 6. ig/fg projections
    gateproj<<<MROWS_, 64, 0, stream>>>(q, kbuf, vbuf, m_Wig, m_big, m_Wfg, m_bfg, igp, fgp);
    // 7. decay precompute
    mlstm_scan_pre<<<B_*NH_, 1024, 0, stream>>>(igp, fgp, lc, av, mx);
    // 8. attention (tiled)
    mlstm_attn_tiled<<<B_*NH_*16, 256, 0, stream>>>(q, kbuf, vbuf, lc, av, mx, hc);
    // 9. multihead LN + skip + gate
    mlstm_out<<<MROWS_, 256, 0, stream>>>(hc, xc, up, m_onw, m_skip, hs);
    // 10. h += hs @ m_Wd^T + m_bd
    gemm_bias_big<<<dim3(128/64, MROWS_/64), 256, 0, stream>>>(hs, m_Wd, m_bd, h, h, MROWS_, 128, 256);
    // 11. r = LN(h)*ln1_w
    ln_kernel<<<MROWS_, 128, 0, stream>>>(h, ln1_w, r);
    // 12. rc = silu(causal_conv(r))
    conv_silu<<<(MROWS_*128)/256, 256, 0, stream>>>(r, 128, s_convk, s_convb, rc, 128, 128);
    // 13. sLSTM gates (all 4 in one launch)
    slstm_gates<<<(MROWS_*128)/256, 256, 0, stream>>>(rc, r, s_Wi, s_Wf, s_Wz, s_Wo, gx);
    // 14. sequential scan (pair-lane layout, DPP exchange)
    slstm_scan_wave<<<B_*NH_, 64, 0, stream>>>(gx, s_R, s_b, ys);
    // 15. h += mh_ln(ys)*s_gnw
    slstm_addnorm<<<MROWS_, 128, 0, stream>>>(ys, s_gnw, h);
    // 16. r = LN(h)*ffn_nw
    ln_kernel<<<MROWS_, 128, 0, stream>>>(h, ffn_nw, r);
    // 17. u = r @ f_Wu^T + f_bu
    gemm_bias_big<<<dim3(384/64, MROWS_/64), 256, 0, stream>>>(r, f_Wu, f_bu, nullptr, u, MROWS_, 384, 128);
    // 18. act = gelu(g)*u2
    ffn_act<<<(MROWS_*192)/256, 256, 0, stream>>>(u, act);
    // 19. h += act @ f_Wd^T + f_bd
    gemm_bias_big<<<dim3(128/64, MROWS_/64), 256, 0, stream>>>(act, f_Wd, f_bd, h, h, MROWS_, 128, 192);
    // 20. hp = LN(h)*post_w
    ln_kernel<<<MROWS_, 128, 0, stream>>>(h, post_w, hp);
    // 21. out = hp[:, -1, :] @ fc_W^T + fc_b
    final_fc<<<B_, 64, 0, stream>>>(hp, fc_W, fc_b, out);
    (void)in_sizes; (void)n_in; (void)out_size; (void)ws_size;
}

// Round 11
// 915.621 us; speedup vs baseline: 1.3752x; 1.0458x over previous
//
#include <hip/hip_runtime.h>
#include <hip/hip_bf16.h>
#include <math.h>

#define B_ 8
#define S_ 1024
#define F_ 75
#define D_ 128
#define INNER_ 256
#define NH_ 4
#define DH_ 64
#define MROWS_ (B_*S_)   // 8192

static __device__ __forceinline__ float frcp(float x){ return __builtin_amdgcn_rcpf(x); }
static __device__ __forceinline__ float fsigm(float x){ return frcp(1.0f + __expf(-x)); }
static __device__ __forceinline__ float flogsig(float x){
    return fminf(x, 0.f) - __logf(1.0f + __expf(-fabsf(x)));
}
static __device__ __forceinline__ float ftanh(float z){
    return 1.0f - 2.0f*frcp(__expf(2.0f*z) + 1.0f);
}

// ---------------- Tiled GEMM: C = A @ W^T + bias (+ res) ----------------
__global__ __launch_bounds__(256, 2) void gemm_bias_big(
        const float* __restrict__ A, const float* __restrict__ W,
        const float* __restrict__ bias, const float* __restrict__ res,
        float* __restrict__ C, int M, int N, int K) {
    __shared__ float As[64*68];
    __shared__ float Ws[64*68];
    int tid = threadIdx.x;
    int wid = tid >> 6, lane = tid & 63;
    int wy = wid >> 1, wx = wid & 1;
    int sg = lane >> 3, tg = lane & 7;
    int m0 = blockIdx.y*64, n0 = blockIdx.x*64;
    int r = tid >> 2, c0 = (tid & 3) << 4;
    bool vec = ((K & 3) == 0);
    float acc[4][4];
    #pragma unroll
    for (int i = 0; i < 4; ++i)
        #pragma unroll
        for (int j = 0; j < 4; ++j) acc[i][j] = 0.f;

    for (int k0 = 0; k0 < K; k0 += 64) {
        __syncthreads();
        const float* Ar = A + (size_t)(m0+r)*K + k0;
        const float* Wr = W + (size_t)(n0+r)*K + k0;
        if (vec) {
            #pragma unroll
            for (int i = 0; i < 4; ++i) {
                *(float4*)(&As[r*68 + c0 + 4*i]) = *(const float4*)(Ar + c0 + 4*i);
                *(float4*)(&Ws[r*68 + c0 + 4*i]) = *(const float4*)(Wr + c0 + 4*i);
            }
        } else {
            #pragma unroll
            for (int i = 0; i < 4; ++i)
                #pragma unroll
                for (int e = 0; e < 4; ++e) {
                    int c = c0 + 4*i + e;
                    bool ok = (k0 + c) < K;
                    As[r*68 + c] = ok ? Ar[c] : 0.f;
                    Ws[r*68 + c] = ok ? Wr[c] : 0.f;
                }
        }
        __syncthreads();
        const float* arow = &As[(32*wy + sg)*68];
        const float* brow = &Ws[(32*wx + tg)*68];
        #pragma unroll 2
        for (int d = 0; d < 64; d += 4) {
            float4 b0 = *(const float4*)(brow + 0*544 + d);
            float4 b1 = *(const float4*)(brow + 1*544 + d);
            float4 b2 = *(const float4*)(brow + 2*544 + d);
            float4 b3 = *(const float4*)(brow + 3*544 + d);
            #pragma unroll
            for (int i = 0; i < 4; ++i) {
                float4 a = *(const float4*)(arow + i*544 + d);
                acc[i][0] += a.x*b0.x + a.y*b0.y + a.z*b0.z + a.w*b0.w;
                acc[i][1] += a.x*b1.x + a.y*b1.y + a.z*b1.z + a.w*b1.w;
                acc[i][2] += a.x*b2.x + a.y*b2.y + a.z*b2.z + a.w*b2.w;
                acc[i][3] += a.x*b3.x + a.y*b3.y + a.z*b3.z + a.w*b3.w;
            }
        }
    }
    #pragma unroll
    for (int i = 0; i < 4; ++i) {
        int m = m0 + 32*wy + 8*i + sg;
        #pragma unroll
        for (int j = 0; j < 4; ++j) {
            int n = n0 + 32*wx + 8*j + tg;
            float v = acc[i][j] + bias[n];
            if (res) v += res[(size_t)m*N + n];
            C[(size_t)m*N + n] = v;
        }
    }
}

// ---------------- Plain LayerNorm over D=128 ----------------
__global__ void ln_kernel(const float* __restrict__ X, const float* __restrict__ w,
                          float* __restrict__ Y) {
    int row = blockIdx.x, t = threadIdx.x;  // 128 threads
    float v = X[(size_t)row*128 + t];
    __shared__ float s1[128], s2[128];
    s1[t]=v; s2[t]=v*v; __syncthreads();
    for (int off=64; off>0; off>>=1){
        if (t<off){ s1[t]+=s1[t+off]; s2[t]+=s2[t+off]; }
        __syncthreads();
    }
    float mu = s1[0]*(1.f/128.f);
    float var = s2[0]*(1.f/128.f) - mu*mu;
    Y[(size_t)row*128 + t] = (v-mu)*rsqrtf(var+1e-5f)*w[t];
}

// ---------------- FUSED mLSTM front-end: conv+silu, q/k/v headwise, gateproj ----------------
// One wave per (b,s) row. Lane l owns head l (channels 4l..4l+3): conv outputs
// feed q/k with zero cross-lane traffic; v comes from the lane's own xm values.
// gateproj partials reduced with the 64-lane butterfly.
__global__ __launch_bounds__(64) void mlstm_qkv(
        const float* __restrict__ up, const float* __restrict__ convk,
        const float* __restrict__ convb,
        const float* __restrict__ Wq, const float* __restrict__ bq,
        const float* __restrict__ Wk, const float* __restrict__ bk,
        const float* __restrict__ Wv, const float* __restrict__ bv,
        const float* __restrict__ Wig, const float* __restrict__ big,
        const float* __restrict__ Wfg, const float* __restrict__ bfg,
        float* __restrict__ xc, float* __restrict__ q, float* __restrict__ k,
        float* __restrict__ v, float* __restrict__ igp, float* __restrict__ fgp) {
    int row = blockIdx.x;
    int b = row >> 10, s = row & 1023;
    int l = threadIdx.x;
    int c0 = l*4;
    // stage the 4 xm rows (s-3..s) for this lane's 4 channels
    float4 xm[4];
    #pragma unroll
    for (int i = 0; i < 4; ++i) {
        int sp = s - 3 + i;
        if (sp >= 0) xm[i] = *(const float4*)(up + (size_t)(row-3+i)*512 + c0);
        else         xm[i] = make_float4(0.f,0.f,0.f,0.f);
    }
    // conv + silu for 4 channels
    float xcv[4];
    #pragma unroll
    for (int j = 0; j < 4; ++j) {
        int c = c0 + j;
        float acc = convb[c];
        #pragma unroll
        for (int i = 0; i < 4; ++i)
            acc += ((const float*)&xm[i])[j] * convk[c*4+i];
        xcv[j] = acc * fsigm(acc);
    }
    *(float4*)(xc + (size_t)row*256 + c0) = make_float4(xcv[0],xcv[1],xcv[2],xcv[3]);
    // q,k from conv outputs; v from xm row s (xm[3])
    float qv[4], kv[4], vv[4];
    #pragma unroll
    for (int o = 0; o < 4; ++o) {
        const float* wq = Wq + ((size_t)l*4 + o)*4;
        const float* wk = Wk + ((size_t)l*4 + o)*4;
        const float* wv = Wv + ((size_t)l*4 + o)*4;
        float aq = bq[c0+o], ak = bk[c0+o], avv = bv[c0+o];
        #pragma unroll
        for (int i = 0; i < 4; ++i) {
            aq  += xcv[i]*wq[i];
            ak  += xcv[i]*wk[i];
            avv += ((const float*)&xm[3])[i]*wv[i];
        }
        qv[o]=aq; kv[o]=ak; vv[o]=avv;
    }
    *(float4*)(q + (size_t)row*256 + c0) = make_float4(qv[0],qv[1],qv[2],qv[3]);
    *(float4*)(k + (size_t)row*256 + c0) = make_float4(kv[0],kv[1],kv[2],kv[3]);
    *(float4*)(v + (size_t)row*256 + c0) = make_float4(vv[0],vv[1],vv[2],vv[3]);
    // gateproj over concat(q,k,v)
    float dots[8];
    #pragma unroll
    for (int g = 0; g < 4; ++g) {
        float di = 0.f, df = 0.f;
        #pragma unroll
        for (int j = 0; j < 4; ++j) {
            di += qv[j]*Wig[g*768 + c0 + j] + kv[j]*Wig[g*768 + 256 + c0 + j]
                + vv[j]*Wig[g*768 + 512 + c0 + j];
            df += qv[j]*Wfg[g*768 + c0 + j] + kv[j]*Wfg[g*768 + 256 + c0 + j]
                + vv[j]*Wfg[g*768 + 512 + c0 + j];
        }
        dots[g] = di; dots[4+g] = df;
    }
    #pragma unroll
    for (int off = 32; off > 0; off >>= 1)
        #pragma unroll
        for (int g = 0; g < 8; ++g) dots[g] += __shfl_down(dots[g], off, 64);
    if (l == 0) {
        #pragma unroll
        for (int g = 0; g < 4; ++g) {
            igp[((size_t)b*NH_+g)*S_ + s] = dots[g]   + big[g];
            fgp[((size_t)b*NH_+g)*S_ + s] = dots[4+g] + bfg[g];
        }
    }
}

// ---------------- FUSED sLSTM front-end: conv+silu + all-4-gate matvecs ----------------
__global__ __launch_bounds__(128) void slstm_convgates(
        const float* __restrict__ r, const float* __restrict__ convk,
        const float* __restrict__ convb, const float* __restrict__ Wi,
        const float* __restrict__ Wf, const float* __restrict__ Wz,
        const float* __restrict__ Wo, float* __restrict__ GX) {
    int row = blockIdx.x; int s = row & 1023;
    int c = threadIdx.x;
    __shared__ float rcL[128], rL[128];
    float rv = r[(size_t)row*128 + c];
    float acc = convb[c];
    #pragma unroll
    for (int i = 0; i < 4; ++i) {
        int sp = s - 3 + i;
        if (sp >= 0) acc += r[(size_t)(row-3+i)*128 + c]*convk[c*4+i];
    }
    float rcv = acc * fsigm(acc);
    rcL[c] = rcv; rL[c] = rv;
    __syncthreads();
    int h = c >> 5, o = c & 31;
    size_t wb = ((size_t)h*32 + o)*32;
    const float* rc_ = rcL + h*32;
    const float* rr_ = rL + h*32;
    float di=0.f, df=0.f, dz=0.f, doo=0.f;
    #pragma unroll
    for (int i = 0; i < 32; ++i) {
        float a = rc_[i], cc = rr_[i];
        di  += a*Wi[wb+i];
        df  += a*Wf[wb+i];
        dz  += cc*Wz[wb+i];
        doo += cc*Wo[wb+i];
    }
    float* g = GX + (size_t)row*512 + h*128 + o;
    g[0]  = di;
    g[32] = df;
    g[64] = dz;
    g[96] = doo;
}

// ---------------- mLSTM decay precompute ----------------
__global__ void mlstm_scan_pre(const float* __restrict__ igp, const float* __restrict__ fgp,
                               float* __restrict__ lc, float* __restrict__ av,
                               float* __restrict__ mx) {
    int bh = blockIdx.x; int t = threadIdx.x;  // 1024 threads
    __shared__ float buf[2][1024];
    float ls = flogsig(fgp[(size_t)bh*S_ + t]);
    int cur = 0;
    buf[0][t] = ls; __syncthreads();
    for (int off=1; off<1024; off<<=1) {
        float x2 = buf[cur][t];
        if (t >= off) x2 += buf[cur][t-off];
        buf[cur^1][t] = x2; cur ^= 1; __syncthreads();
    }
    float lcv = buf[cur][t];
    lc[(size_t)bh*S_+t] = lcv;
    float a = igp[(size_t)bh*S_+t] - lcv;
    av[(size_t)bh*S_+t] = a;
    __syncthreads();
    cur = 0; buf[0][t] = a; __syncthreads();
    for (int off=1; off<1024; off<<=1) {
        float x2 = buf[cur][t];
        if (t >= off) x2 = fmaxf(x2, buf[cur][t-off]);
        buf[cur^1][t] = x2; cur ^= 1; __syncthreads();
    }
    mx[(size_t)bh*S_+t] = buf[cur][t];
}

// ---------------- mLSTM attention: tiled flash-style ----------------
__global__ __launch_bounds__(256, 2) void mlstm_attn_tiled(
        const float* __restrict__ q, const float* __restrict__ k,
        const float* __restrict__ v, const float* __restrict__ lc,
        const float* __restrict__ av, const float* __restrict__ mx,
        float* __restrict__ hc) {
    int bid = blockIdx.x;
    int stile = 15 - (bid & 15);
    int bh = bid >> 4;
    int hh = bh & 3, b = bh >> 2;
    int s0 = stile << 6;
    int tid = threadIdx.x;
    int wid = tid >> 6, lane = tid & 63;
    int wy = wid >> 1, wx = wid & 1;
    int sg = lane >> 3, tg = lane & 7;

    __shared__ float qs[64*68];
    __shared__ float kst[64*68];
    __shared__ float vtT[64*68];
    __shared__ float avt[64], maxsL[64], normL[64], rsumL[128];

    const size_t bhS = (size_t)bh * S_;
    {
        int r = tid >> 2, c0 = (tid & 3) << 4;
        const float* qg = q + ((size_t)(b*S_) + s0 + r)*INNER_ + hh*64;
        #pragma unroll
        for (int i = 0; i < 4; ++i) {
            float4 t4 = *(const float4*)(qg + c0 + 4*i);
            float4 w4; w4.x=t4.x*0.125f; w4.y=t4.y*0.125f; w4.z=t4.z*0.125f; w4.w=t4.w*0.125f;
            *(float4*)(&qs[r*68 + c0 + 4*i]) = w4;
        }
        if (tid < 64) maxsL[tid] = lc[bhS + s0 + tid] + mx[bhS + s0 + tid];
    }
    float msv[4];
    #pragma unroll
    for (int i = 0; i < 4; ++i)
        msv[i] = mx[bhS + s0 + 32*wy + 8*i + sg];

    float O[4][4];
    float rsAcc[4];
    #pragma unroll
    for (int i = 0; i < 4; ++i) {
        rsAcc[i] = 0.f;
        #pragma unroll
        for (int j = 0; j < 4; ++j) O[i][j] = 0.f;
    }

    for (int t0 = 0; t0 <= s0; t0 += 64) {
        __syncthreads();
        {
            int r = tid >> 2, c0 = (tid & 3) << 4;
            const float* kg = k + ((size_t)(b*S_) + t0 + r)*INNER_ + hh*64;
            const float* vg = v + ((size_t)(b*S_) + t0 + r)*INNER_ + hh*64;
            #pragma unroll
            for (int i = 0; i < 4; ++i) {
                *(float4*)(&kst[r*68 + c0 + 4*i]) = *(const float4*)(kg + c0 + 4*i);
                float4 v4 = *(const float4*)(vg + c0 + 4*i);
                int dc = c0 + 4*i;
                vtT[(dc+0)*68 + r] = v4.x;
                vtT[(dc+1)*68 + r] = v4.y;
                vtT[(dc+2)*68 + r] = v4.z;
                vtT[(dc+3)*68 + r] = v4.w;
            }
            if (tid < 64) avt[tid] = av[bhS + t0 + tid];
        }
        __syncthreads();
        float dot[4][4];
        #pragma unroll
        for (int i = 0; i < 4; ++i)
            #pragma unroll
            for (int j = 0; j < 4; ++j) dot[i][j] = 0.f;
        {
            const float* qrow = &qs[(32*wy + sg)*68];
            const float* krow = &kst[(32*wx + tg)*68];
            #pragma unroll 2
            for (int d = 0; d < 64; d += 4) {
                float4 b0 = *(const float4*)(krow + 0*544 + d);
                float4 b1 = *(const float4*)(krow + 1*544 + d);
                float4 b2 = *(const float4*)(krow + 2*544 + d);
                float4 b3 = *(const float4*)(krow + 3*544 + d);
                #pragma unroll
                for (int i = 0; i < 4; ++i) {
                    float4 a = *(const float4*)(qrow + i*544 + d);
                    dot[i][0] += a.x*b0.x + a.y*b0.y + a.z*b0.z + a.w*b0.w;
                    dot[i][1] += a.x*b1.x + a.y*b1.y + a.z*b1.z + a.w*b1.w;
                    dot[i][2] += a.x*b2.x + a.y*b2.y + a.z*b2.z + a.w*b2.w;
                    dot[i][3] += a.x*b3.x + a.y*b3.y + a.z*b3.z + a.w*b3.w;
                }
            }
        }
        __syncthreads();
        #pragma unroll
        for (int i = 0; i < 4; ++i) {
            int s_loc = 32*wy + 8*i + sg;
            float rp = 0.f;
            #pragma unroll
            for (int j = 0; j < 4; ++j) {
                int t_loc = 32*wx + 8*j + tg;
                bool ok = (t0 + t_loc) <= (s0 + s_loc);
                float p = ok ? dot[i][j]*__expf(avt[t_loc] - msv[i]) : 0.f;
                kst[s_loc*68 + t_loc] = p;
                rp += p;
            }
            rp += __shfl_xor(rp, 1);
            rp += __shfl_xor(rp, 2);
            rp += __shfl_xor(rp, 4);
            rsAcc[i] += rp;
        }
        __syncthreads();
        {
            const float* prow = &kst[(32*wy + sg)*68];
            const float* vrow = &vtT[(32*wx + tg)*68];
            #pragma unroll 2
            for (int tt = 0; tt < 64; tt += 4) {
                float4 b0 = *(const float4*)(vrow + 0*544 + tt);
                float4 b1 = *(const float4*)(vrow + 1*544 + tt);
                float4 b2 = *(const float4*)(vrow + 2*544 + tt);
                float4 b3 = *(const float4*)(vrow + 3*544 + tt);
                #pragma unroll
                for (int i = 0; i < 4; ++i) {
                    float4 a = *(const float4*)(prow + i*544 + tt);
                    O[i][0] += a.x*b0.x + a.y*b0.y + a.z*b0.z + a.w*b0.w;
                    O[i][1] += a.x*b1.x + a.y*b1.y + a.z*b1.z + a.w*b1.w;
                    O[i][2] += a.x*b2.x + a.y*b2.y + a.z*b2.z + a.w*b2.w;
                    O[i][3] += a.x*b3.x + a.y*b3.y + a.z*b3.z + a.w*b3.w;
                }
            }
        }
    }
    if (tg == 0) {
        #pragma unroll
        for (int i = 0; i < 4; ++i)
            rsumL[wx*64 + 32*wy + 8*i + sg] = rsAcc[i];
    }
    __syncthreads();
    if (tid < 64) {
        float tot = rsumL[tid] + rsumL[64 + tid];
        normL[tid] = fmaxf(fabsf(tot), __expf(-maxsL[tid])) + 1e-6f;
    }
    __syncthreads();
    #pragma unroll
    for (int i = 0; i < 4; ++i) {
        int s_loc = 32*wy + 8*i + sg;
        float inv = 1.0f / normL[s_loc];
        #pragma unroll
        for (int j = 0; j < 4; ++j) {
            int d_loc = 32*wx + 8*j + tg;
            hc[((size_t)(b*S_) + s0 + s_loc)*INNER_ + hh*64 + d_loc] = O[i][j] * inv;
        }
    }
}

// ---------------- mLSTM output: multihead LN (GS=64) + skip + gate ----------------
__global__ void mlstm_out(const float* __restrict__ hc, const float* __restrict__ xc,
                          const float* __restrict__ up, const float* __restrict__ onw,
                          const float* __restrict__ skip, float* __restrict__ hs) {
    int row = blockIdx.x; int c = threadIdx.x;  // 256 threads
    float v = hc[(size_t)row*INNER_ + c];
    __shared__ float s1[256], s2[256];
    s1[c]=v; s2[c]=v*v; __syncthreads();
    int li = c & 63;
    for (int off=32; off>0; off>>=1){
        if (li < off){ s1[c]+=s1[c+off]; s2[c]+=s2[c+off]; }
        __syncthreads();
    }
    int base = c & ~63;
    float mu = s1[base]*(1.f/64.f);
    float var = s2[base]*(1.f/64.f) - mu*mu;
    float ht = (v-mu)*rsqrtf(var+1e-5f)*onw[c];
    float z = up[(size_t)row*512 + 256 + c];
    hs[(size_t)row*INNER_ + c] = (ht + skip[c]*xc[(size_t)row*INNER_+c]) * (z*fsigm(z));
}

// ---------------- sLSTM scan: pair-lane layout, DPP gate exchange ----------------
__global__ __launch_bounds__(64, 1) void slstm_scan_wave(
        const float* __restrict__ gx, const float* __restrict__ R,
        const float* __restrict__ bb, float* __restrict__ ys) {
    int blk = blockIdx.x; int hh = blk & 3; int b = blk >> 2;
    int l = threadIdx.x;  // 0..63
    int e = l >> 1, p = l & 1;
    int o0 = p*32 + e, o1 = (p+2)*32 + e;
    float Rc0[32], Rc1[32];
    #pragma unroll
    for (int d = 0; d < 32; ++d) {
        Rc0[d] = R[(size_t)(hh*32 + d)*128 + o0];
        Rc1[d] = R[(size_t)(hh*32 + d)*128 + o1];
        asm volatile("" : "+v"(Rc0[d]));
        asm volatile("" : "+v"(Rc1[d]));
    }
    float bj0 = bb[hh*128 + o0], bj1 = bb[hh*128 + o1];
    float cst = 0.f, nst = 0.f, mst = 0.f, y = 0.f;
    const float* gbase = gx + (size_t)(b*S_)*512 + hh*128;
    float* ybase = ys + (size_t)(b*S_)*128 + hh*32 + e;
    float ga[4], gb[4];
    #pragma unroll
    for (int u = 0; u < 4; ++u) {
        ga[u] = gbase[(size_t)u*512 + o0];
        gb[u] = gbase[(size_t)u*512 + o1];
    }
    for (int t = 0; t < S_; t += 4) {
        float gna[4], gnb[4];
        #pragma unroll
        for (int u = 0; u < 4; ++u) {
            int tn = t + 4 + u;
            size_t off = (size_t)(tn < S_ ? tn : 0) * 512;
            gna[u] = gbase[off + o0];
            gnb[u] = gbase[off + o1];
        }
        #pragma unroll
        for (int u = 0; u < 4; ++u) {
            float a0=0.f, a1=0.f, a2=0.f, a3=0.f;
            float c0=0.f, c1=0.f, c2=0.f, c3=0.f;
            #pragma unroll
            for (int d = 0; d < 32; d += 4) {
                float y0 = __int_as_float(__builtin_amdgcn_readlane(__float_as_int(y), 2*d));
                float y1 = __int_as_float(__builtin_amdgcn_readlane(__float_as_int(y), 2*d+2));
                float y2 = __int_as_float(__builtin_amdgcn_readlane(__float_as_int(y), 2*d+4));
                float y3 = __int_as_float(__builtin_amdgcn_readlane(__float_as_int(y), 2*d+6));
                a0 += y0*Rc0[d];   c0 += y0*Rc1[d];
                a1 += y1*Rc0[d+1]; c1 += y1*Rc1[d+1];
                a2 += y2*Rc0[d+2]; c2 += y2*Rc1[d+2];
                a3 += y3*Rc0[d+3]; c3 += y3*Rc1[d+3];
            }
            float r0 = ga[u] + bj0 + ((a0+a1)+(a2+a3));
            float r1 = gb[u] + bj1 + ((c0+c1)+(c2+c3));
            float fo0 = __int_as_float(__builtin_amdgcn_mov_dpp(__float_as_int(r0), 0xB1, 0xF, 0xF, true));
            float fo1 = __int_as_float(__builtin_amdgcn_mov_dpp(__float_as_int(r1), 0xB1, 0xF, 0xF, true));
            float iraw = p ? fo0 : r0;
            float fraw = p ? r0 : fo0;
            float zraw = p ? fo1 : r1;
            float oraw = p ? r1 : fo1;
            int t_abs = t + u;
            float lfm = mst + flogsig(fraw);
            float mnew = (t_abs == 0) ? iraw : fmaxf(iraw, lfm);
            float igv = __expf(iraw - mnew), fgv = __expf(lfm - mnew);
            cst = fgv*cst + igv*ftanh(zraw);
            nst = fgv*nst + igv;
            mst = mnew;
            y = cst * frcp(nst * (1.0f + __expf(-oraw)));
            if (p == 0) ybase[(size_t)t_abs*128] = y;
        }
        #pragma unroll
        for (int u = 0; u < 4; ++u) { ga[u] = gna[u]; gb[u] = gnb[u]; }
    }
}

// ---------------- FUSED: h += mh_ln(ys; GS=32)*gnw ; r = LN(h)*ffn_nw ----------------
__global__ void slstm_addnorm_ln(const float* __restrict__ ys, const float* __restrict__ gnw,
                                 const float* __restrict__ ffnw,
                                 float* __restrict__ h, float* __restrict__ r) {
    int row = blockIdx.x; int c = threadIdx.x;  // 128
    __shared__ float s1[128], s2[128];
    float v = ys[(size_t)row*128 + c];
    s1[c]=v; s2[c]=v*v; __syncthreads();
    int li = c & 31;
    for (int off=16; off>0; off>>=1){
        if (li < off){ s1[c]+=s1[c+off]; s2[c]+=s2[c+off]; }
        __syncthreads();
    }
    int base = c & ~31;
    float mu = s1[base]*(1.f/32.f);
    float var = s2[base]*(1.f/32.f) - mu*mu;
    float hn = h[(size_t)row*128 + c] + (v-mu)*rsqrtf(var+1e-5f)*gnw[c];
    h[(size_t)row*128 + c] = hn;
    __syncthreads();
    // full-row LN of hn
    s1[c]=hn; s2[c]=hn*hn; __syncthreads();
    for (int off=64; off>0; off>>=1){
        if (c<off){ s1[c]+=s1[c+off]; s2[c]+=s2[c+off]; }
        __syncthreads();
    }
    float mu2 = s1[0]*(1.f/128.f);
    float var2 = s2[0]*(1.f/128.f) - mu2*mu2;
    r[(size_t)row*128 + c] = (hn-mu2)*rsqrtf(var2+1e-5f)*ffnw[c];
}

// ---------------- FFN activation: gelu(g) * u2 ----------------
__global__ void ffn_act(const float* __restrict__ u, float* __restrict__ act) {
    int idx = blockIdx.x*blockDim.x + threadIdx.x;
    int total = MROWS_*192;
    if (idx >= total) return;
    int j = idx % 192; int m = idx / 192;
    float g  = u[(size_t)m*384 + j];
    float u2 = u[(size_t)m*384 + 192 + j];
    float ge = 0.5f*g*(1.0f + erff(g*0.70710678118f));
    act[(size_t)m*192 + j] = ge*u2;
}

// ---------------- FUSED final: LN(last-token rows only) + FC ----------------
__global__ void final_ln_fc(const float* __restrict__ h, const float* __restrict__ postw,
                            const float* __restrict__ fcW, const float* __restrict__ fcb,
                            float* __restrict__ out) {
    int b = blockIdx.x; int t = threadIdx.x;  // 128
    const float* hr = h + (size_t)(b*S_ + S_-1)*128;
    float v = hr[t];
    __shared__ float s1[128], s2[128];
    s1[t]=v; s2[t]=v*v; __syncthreads();
    for (int off=64; off>0; off>>=1){
        if (t<off){ s1[t]+=s1[t+off]; s2[t]+=s2[t+off]; }
        __syncthreads();
    }
    float mu = s1[0]*(1.f/128.f);
    float var = s2[0]*(1.f/128.f) - mu*mu;
    float hp = (v-mu)*rsqrtf(var+1e-5f)*postw[t];
    __syncthreads();
    s1[t] = hp*fcW[t]; __syncthreads();
    for (int off=64; off>0; off>>=1){
        if (t<off) s1[t]+=s1[t+off];
        __syncthreads();
    }
    if (t == 0) out[b] = s1[0] + fcb[0];
}

extern "C" void kernel_launch(void* const* d_in, const int* in_sizes, int n_in,
                              void* d_out, int out_size, void* d_ws, size_t ws_size,
                              hipStream_t stream) {
    const float* x       = (const float*)d_in[0];
    const float* W_in    = (const float*)d_in[1];
    const float* b_in    = (const float*)d_in[2];
    const float* ln0_w   = (const float*)d_in[3];
    const float* m_Wup   = (const float*)d_in[4];
    const float* m_bup   = (const float*)d_in[5];
    const float* m_convk = (const float*)d_in[6];
    const float* m_convb = (const float*)d_in[7];
    const float* m_Wq    = (const float*)d_in[8];
    const float* m_bq    = (const float*)d_in[9];
    const float* m_Wk    = (const float*)d_in[10];
    const float* m_bk    = (const float*)d_in[11];
    const float* m_Wv    = (const float*)d_in[12];
    const float* m_bv    = (const float*)d_in[13];
    const float* m_Wig   = (const float*)d_in[14];
    const float* m_big   = (const float*)d_in[15];
    const float* m_Wfg   = (const float*)d_in[16];
    const float* m_bfg   = (const float*)d_in[17];
    const float* m_onw   = (const float*)d_in[18];
    const float* m_skip  = (const float*)d_in[19];
    const float* m_Wd    = (const float*)d_in[20];
    const float* m_bd    = (const float*)d_in[21];
    const float* ln1_w   = (const float*)d_in[22];
    const float* s_convk = (const float*)d_in[23];
    const float* s_convb = (const float*)d_in[24];
    const float* s_Wi    = (const float*)d_in[25];
    const float* s_Wf    = (const float*)d_in[26];
    const float* s_Wz    = (const float*)d_in[27];
    const float* s_Wo    = (const float*)d_in[28];
    const float* s_R     = (const float*)d_in[29];
    const float* s_b     = (const float*)d_in[30];
    const float* s_gnw   = (const float*)d_in[31];
    const float* ffn_nw  = (const float*)d_in[32];
    const float* f_Wu    = (const float*)d_in[33];
    const float* f_bu    = (const float*)d_in[34];
    const float* f_Wd    = (const float*)d_in[35];
    const float* f_bd    = (const float*)d_in[36];
    const float* post_w  = (const float*)d_in[37];
    const float* fc_W    = (const float*)d_in[38];
    const float* fc_b    = (const float*)d_in[39];
    float* out = (float*)d_out;

    float* W = (float*)d_ws;
    const size_t M1 = 1048576;        // 8192*128
    float* h    = W;                   // 1M
    float* r    = W + 1*M1;            // 1M
    float* up   = W + 2*M1;            // 4M
    float* xc   = W + 6*M1;            // 2M
    float* q    = W + 8*M1;            // 2M
    float* kbuf = W + 10*M1;           // 2M
    float* vbuf = W + 12*M1;           // 2M
    float* hc   = W + 14*M1;           // 2M
    float* igp  = W + 16*M1;
    float* fgp  = igp + 32768;
    float* lc   = fgp + 32768;
    float* av   = lc  + 32768;
    float* mx   = av  + 32768;
    float* hs   = q;
    float* gx   = kbuf;
    float* ys   = hc;
    float* u    = up;
    float* act  = q;

    // 1. h = x @ W_in^T + b_in
    gemm_bias_big<<<dim3(128/64, MROWS_/64), 256, 0, stream>>>(x, W_in, b_in, nullptr, h, MROWS_, 128, F_);
    // 2. r = LN(h)*ln0_w
    ln_kernel<<<MROWS_, 128, 0, stream>>>(h, ln0_w, r);
    // 3. up = r @ m_Wup^T + m_bup
    gemm_bias_big<<<dim3(512/64, MROWS_/64), 256, 0, stream>>>(r, m_Wup, m_bup, nullptr, up, MROWS_, 512, 128);
    // 4. FUSED conv+silu + q/k/v headwise + gateproj
    mlstm_qkv<<<MROWS_, 64, 0, stream>>>(up, m_convk, m_convb, m_Wq, m_bq, m_Wk, m_bk,
                                         m_Wv, m_bv, m_Wig, m_big, m_Wfg, m_bfg,
                                         xc, q, kbuf, vbuf, igp, fgp);
    // 5. decay precompute
    mlstm_scan_pre<<<B_*NH_, 1024, 0, stream>>>(igp, fgp, lc, av, mx);
    // 6. attention (tiled)
    mlstm_attn_tiled<<<B_*NH_*16, 256, 0, stream>>>(q, kbuf, vbuf, lc, av, mx, hc);
    // 7. multihead LN + skip + gate
    mlstm_out<<<MROWS_, 256, 0, stream>>>(hc, xc, up, m_onw, m_skip, hs);
    // 8. h += hs @ m_Wd^T + m_bd
    gemm_bias_big<<<dim3(128/64, MROWS_/64), 256, 0, stream>>>(hs, m_Wd, m_bd, h, h, MROWS_, 128, 256);
    // 9. r = LN(h)*ln1_w
    ln_kernel<<<MROWS_, 128, 0, stream>>>(h, ln1_w, r);
    // 10. FUSED sLSTM conv+silu + 4-gate matvecs
    slstm_convgates<<<MROWS_, 128, 0, stream>>>(r, s_convk, s_convb, s_Wi, s_Wf, s_Wz, s_Wo, gx);
    // 11. sequential scan
    slstm_scan_wave<<<B_*NH_, 64, 0, stream>>>(gx, s_R, s_b, ys);
    // 12. FUSED h += mh_ln(ys)*gnw ; r = LN(h)*ffn_nw
    slstm_addnorm_ln<<<MROWS_, 128, 0, stream>>>(ys, s_gnw, ffn_nw, h, r);
    // 13. u = r @ f_Wu^T + f_bu
    gemm_bias_big<<<dim3(384/64, MROWS_/64), 256, 0, stream>>>(r, f_Wu, f_bu, nullptr, u, MROWS_, 384, 128);
    // 14. act = gelu(g)*u2
    ffn_act<<<(MROWS_*192)/256, 256, 0, stream>>>(u, act);
    // 15. h += act @ f_Wd^T + f_bd
    gemm_bias_big<<<dim3(128/64, MROWS_/64), 256, 0, stream>>>(act, f_Wd, f_bd, h, h, MROWS_, 128, 192);
    // 16. FUSED final LN (last token only) + FC
    final_ln_fc<<<B_, 128, 0, stream>>>(h, post_w, fc_W, fc_b, out);
    (void)in_sizes; (void)n_in; (void)out_size; (void)ws_size;
}